// Round 3
// baseline (402.478 us; speedup 1.0000x reference)
//
#include <hip/hip_runtime.h>
#include <hip/hip_bf16.h>
#include <cstdint>
#include <cstddef>

// MultiHeadAttention B=4, S=2048, D=1024, H=16, dk=64. fp32 in/out, bf16 MFMA internals.
// cvt fp32->bf16 -> fused QKV gemm (V written transposed [B,H,dk,S]) -> flash attn
// (512-thr, 8-wave Q128 tile, double-buffered DMA K/V, in-register P^T exchange,
//  defer-max, setprio) -> out proj.

#define BATCH   4
#define SEQ     2048
#define D_MODEL 1024
#define NHEADS  16
#define DK      64

typedef __attribute__((ext_vector_type(8))) __bf16 bf16x8_t;
typedef __attribute__((ext_vector_type(4))) float  f32x4;

// HW packed fp32->bf16 (v_cvt_pk_bf16_f32 on gfx950)
__device__ inline unsigned int pack2(float lo, float hi) {
  __hip_bfloat162 h = __float22bfloat162_rn(make_float2(lo, hi));
  union { __hip_bfloat162 h; unsigned int u; } c; c.h = h; return c.u;
}
__device__ inline unsigned short f2bf(float f) { return (unsigned short)pack2(f, f); }

#if __has_builtin(__builtin_amdgcn_exp2f)
__device__ inline float fexp2(float x) { return __builtin_amdgcn_exp2f(x); }
#else
__device__ inline float fexp2(float x) { return __expf(x * 0.6931471805599453f); }
#endif

__device__ inline void cvt8(const float* __restrict__ s, unsigned short* __restrict__ d) {
  const float4 a = *(const float4*)s;
  const float4 b = *(const float4*)(s + 4);
  uint4 r;
  r.x = pack2(a.x, a.y); r.y = pack2(a.z, a.w);
  r.z = pack2(b.x, b.y); r.w = pack2(b.z, b.w);
  *(uint4*)d = r;
}

// async global->LDS, 16B/lane; LDS dest = wave-uniform base + lane*16B
typedef __attribute__((address_space(3))) unsigned int lds_u32_t;
typedef const __attribute__((address_space(1))) unsigned int glb_u32_t;
__device__ inline void gld16(const unsigned short* g, unsigned short* l) {
  __builtin_amdgcn_global_load_lds((glb_u32_t*)(uintptr_t)g,
                                   (lds_u32_t*)(unsigned int)(uintptr_t)l, 16, 0, 0);
}

// ---------------- fp32 -> bf16 conversion ----------------
__global__ __launch_bounds__(256) void cvt3_kernel(
    const float* __restrict__ a, const float* __restrict__ b, const float* __restrict__ c,
    unsigned short* __restrict__ oa, unsigned short* __restrict__ ob, unsigned short* __restrict__ oc)
{
  const float* s = (blockIdx.y == 0) ? a : (blockIdx.y == 1) ? b : c;
  unsigned short* d = (blockIdx.y == 0) ? oa : (blockIdx.y == 1) ? ob : oc;
  const size_t i = ((size_t)blockIdx.x * 256 + threadIdx.x) * 8;
  cvt8(s + i, d + i);
}
__global__ __launch_bounds__(256) void cvt4_kernel(
    const float* __restrict__ a, const float* __restrict__ b,
    const float* __restrict__ c, const float* __restrict__ dd,
    unsigned short* __restrict__ oa, unsigned short* __restrict__ ob,
    unsigned short* __restrict__ oc, unsigned short* __restrict__ od)
{
  const float* s = (blockIdx.y == 0) ? a : (blockIdx.y == 1) ? b : (blockIdx.y == 2) ? c : dd;
  unsigned short* d = (blockIdx.y == 0) ? oa : (blockIdx.y == 1) ? ob : (blockIdx.y == 2) ? oc : od;
  const size_t i = ((size_t)blockIdx.x * 256 + threadIdx.x) * 8;
  cvt8(s + i, d + i);
}

// ---------------- shared GEMM core: acc += A[128 rows @m0] * W[128 rows @n0]^T ----------------
// m97 structure: BK=32 unpadded LDS, global_load_lds 16B, chunk^(row&3) source-side swizzle.
__device__ inline void gemm_core(const unsigned short* __restrict__ A,
                                 const unsigned short* __restrict__ W,
                                 unsigned short* a_lds, unsigned short* b_lds,
                                 int m0, int n0, f32x4 (&acc)[4][4])
{
  const int tid  = threadIdx.x;
  const int lane = tid & 63;
  const int wv   = tid >> 6;
  const int l15  = lane & 15;
  const int quad = lane >> 4;
  const int wm = (wv & 1) * 64;
  const int wn = (wv >> 1) * 64;

  const int srow = tid >> 2;
  const int sch  = (tid & 3) ^ (srow & 3);
  const unsigned short* Ap0 = A + (size_t)(m0 + srow) * D_MODEL + sch * 8;
  const unsigned short* Ap1 = Ap0 + (size_t)64 * D_MODEL;
  const unsigned short* Wp0 = W + (size_t)(n0 + srow) * D_MODEL + sch * 8;
  const unsigned short* Wp1 = Wp0 + (size_t)64 * D_MODEL;
  unsigned short* al0 = a_lds + wv * 512;
  unsigned short* al1 = a_lds + 2048 + wv * 512;
  unsigned short* bl0 = b_lds + wv * 512;
  unsigned short* bl1 = b_lds + 2048 + wv * 512;

  const int pq = (quad ^ (l15 & 3)) * 8;

  for (int k0 = 0; k0 < D_MODEL; k0 += 32) {
    __syncthreads();
    gld16(Ap0 + k0, al0);
    gld16(Ap1 + k0, al1);
    gld16(Wp0 + k0, bl0);
    gld16(Wp1 + k0, bl1);
    __syncthreads();

    bf16x8_t af[4], bfr[4];
#pragma unroll
    for (int i = 0; i < 4; ++i)
      af[i] = *(const bf16x8_t*)&a_lds[(wm + i * 16 + l15) * 32 + pq];
#pragma unroll
    for (int j = 0; j < 4; ++j)
      bfr[j] = *(const bf16x8_t*)&b_lds[(wn + j * 16 + l15) * 32 + pq];

#pragma unroll
    for (int i = 0; i < 4; ++i)
#pragma unroll
      for (int j = 0; j < 4; ++j)
        acc[i][j] = __builtin_amdgcn_mfma_f32_16x16x32_bf16(af[i], bfr[j], acc[i][j], 0, 0, 0);
  }
}

// ---------------- fused QKV projection ----------------
// grid (M/128, N/128, 3). z=0: Q (scaled log2e/8, scatter [B,H,S,dk]); z=1: K (scatter);
// z=2: V written TRANSPOSED [B,H,dk,S].
__global__ __launch_bounds__(256) void qkv_kernel(
    const unsigned short* __restrict__ qb, const unsigned short* __restrict__ kb,
    const unsigned short* __restrict__ vb,
    const unsigned short* __restrict__ wq, const unsigned short* __restrict__ wk,
    const unsigned short* __restrict__ wvp,
    const float* __restrict__ bq, const float* __restrict__ bk, const float* __restrict__ bv,
    unsigned short* __restrict__ Qws, unsigned short* __restrict__ Kws,
    unsigned short* __restrict__ Vws)
{
  __shared__ unsigned short a_lds[128 * 32];
  __shared__ unsigned short b_lds[128 * 32];

  const int z = blockIdx.z;
  const unsigned short* A = (z == 0) ? qb : (z == 1) ? kb : vb;
  const unsigned short* W = (z == 0) ? wq : (z == 1) ? wk : wvp;
  const float* bias       = (z == 0) ? bq : (z == 1) ? bk : bv;
  unsigned short* C       = (z == 0) ? Qws : (z == 1) ? Kws : Vws;
  const int m0 = blockIdx.x * 128;
  const int n0 = blockIdx.y * 128;

  f32x4 acc[4][4];
#pragma unroll
  for (int i = 0; i < 4; ++i)
#pragma unroll
    for (int j = 0; j < 4; ++j)
      acc[i][j] = (f32x4){0.f, 0.f, 0.f, 0.f};

  gemm_core(A, W, a_lds, b_lds, m0, n0, acc);

  const int tid  = threadIdx.x;
  const int lane = tid & 63;
  const int wv   = tid >> 6;
  const int l15  = lane & 15;
  const int quad = lane >> 4;
  const int wm = (wv & 1) * 64;
  const int wn = (wv >> 1) * 64;
  // C/D layout: col = lane&15, row = quad*4 + reg  [m89]
  if (z == 2) {
    // V^T: off = ((bb*H+hh)*DK+dd)*SEQ + ss; 4 consecutive ss per lane -> uint2
    for (int j = 0; j < 4; ++j) {
      const int n = n0 + wn + j * 16 + l15;
      const int hh = n >> 6, dd = n & 63;
      const float bvl = bias[n];
      for (int i = 0; i < 4; ++i) {
        const int mbase = m0 + wm + i * 16 + quad * 4;
        const int bb = mbase >> 11, ss = mbase & 2047;
        uint2 w2 = make_uint2(pack2(acc[i][j][0] + bvl, acc[i][j][1] + bvl),
                              pack2(acc[i][j][2] + bvl, acc[i][j][3] + bvl));
        *(uint2*)(C + (((size_t)bb * NHEADS + hh) * DK + dd) * SEQ + ss) = w2;
      }
    }
  } else {
    const float oscale = (z == 0) ? 0.18033688011112042f : 1.0f;  // log2(e)/8 for Q
    for (int j = 0; j < 4; ++j) {
      const int n = n0 + wn + j * 16 + l15;
      const int hh = n >> 6, dd = n & 63;
      const float bvl = bias[n];
      for (int i = 0; i < 4; ++i) {
        const int mbase = m0 + wm + i * 16 + quad * 4;
        const int bb = mbase >> 11, ss = mbase & 2047;
        unsigned short* dst = C + (((size_t)bb * NHEADS + hh) * SEQ + ss) * DK + dd;
        for (int r = 0; r < 4; ++r)
          dst[(size_t)r * DK] = f2bf((acc[i][j][r] + bvl) * oscale);
      }
    }
  }
}

// ---------------- output projection (bf16 A, fp32 out) ----------------
__global__ __launch_bounds__(256) void outproj_kernel(
    const unsigned short* __restrict__ A, const unsigned short* __restrict__ W,
    const float* __restrict__ bias, float* __restrict__ C)
{
  __shared__ unsigned short a_lds[128 * 32];
  __shared__ unsigned short b_lds[128 * 32];
  const int m0 = blockIdx.x * 128;
  const int n0 = blockIdx.y * 128;

  f32x4 acc[4][4];
#pragma unroll
  for (int i = 0; i < 4; ++i)
#pragma unroll
    for (int j = 0; j < 4; ++j)
      acc[i][j] = (f32x4){0.f, 0.f, 0.f, 0.f};

  gemm_core(A, W, a_lds, b_lds, m0, n0, acc);

  const int tid  = threadIdx.x;
  const int lane = tid & 63;
  const int wv   = tid >> 6;
  const int l15  = lane & 15;
  const int quad = lane >> 4;
  const int wm = (wv & 1) * 64;
  const int wn = (wv >> 1) * 64;
  for (int j = 0; j < 4; ++j) {
    const int n = n0 + wn + j * 16 + l15;
    const float bvl = bias[n];
    for (int i = 0; i < 4; ++i) {
      const int mbase = m0 + wm + i * 16 + quad * 4;
      for (int r = 0; r < 4; ++r)
        C[(size_t)(mbase + r) * D_MODEL + n] = acc[i][j][r] + bvl;
    }
  }
}

// ---------------- Flash attention, S^T form ----------------
// 512 thr (8 waves), Q-tile 128 rows; grid (B*H, S/128). Wave wv owns q-rows q0+wv*16+l15.
// K/V^T DMA-staged double-buffered (each wave stages 8 rows K + 8 rows V^T = 2 gld16).
// S^T = K*Q^T; per-lane softmax (base-2; Q pre-scaled by log2e/8, defer-max THR=8);
// P^T redistributed IN-REGISTER via shuffles (no LDS round-trip); O^T = V^T*P^T.
// LDS tiles stride 64, source-side XOR swizzle chunk^(row&7)^(row>>3). 32 KiB LDS total.
// launch_bounds (512,6): ~84-VGPR budget -> 3 blocks/CU = 24 waves/CU without spill.
__global__ __launch_bounds__(512, 6) void attn_kernel(
    const unsigned short* __restrict__ Q,    // [B,H,S,dk]
    const unsigned short* __restrict__ K,    // [B,H,S,dk]
    const unsigned short* __restrict__ Vt,   // [B,H,dk,S]  (pre-transposed)
    unsigned short* __restrict__ Oattn)      // [B,S,D]
{
  __shared__ unsigned short k_sw[2 * 64 * 64];
  __shared__ unsigned short vt_sw[2 * 64 * 64];

  const int tid  = threadIdx.x;
  const int lane = tid & 63;
  const int wv   = tid >> 6;              // 0..7
  const int l15  = lane & 15;
  const int quad = lane >> 4;
  const int bh   = blockIdx.x;            // bh-major: XCD = bh%8 -> K/V L2 locality
  const int q0   = blockIdx.y * 128;
  const size_t hoff = (size_t)bh * SEQ * DK;
  const unsigned short* Qh  = Q  + hoff;
  const unsigned short* Kh  = K  + hoff;
  const unsigned short* Vth = Vt + hoff;

  bf16x8_t qf0, qf1;
  {
    const unsigned short* qr = Qh + (size_t)(q0 + wv * 16 + l15) * DK;
    qf0 = *(const bf16x8_t*)(qr + quad * 8);
    qf1 = *(const bf16x8_t*)(qr + 32 + quad * 8);
  }

  f32x4 o[4];
#pragma unroll
  for (int t = 0; t < 4; ++t) o[t] = (f32x4){0.f, 0.f, 0.f, 0.f};
  float mval = -1e30f, lval = 0.f;

  // DMA staging: wave wv covers tile rows [wv*8, wv*8+8) of K and of V^T (1 gld16 each).
  const int sr  = lane >> 3;              // 0..7 (row within the wave's 8-row slab)
  const int pc  = lane & 7;               // phys chunk
  const int row = wv * 8 + sr;
  const int sem = pc ^ sr ^ wv;           // (row&7)=sr, (row>>3)=wv
  const unsigned short* KsA = Kh  + (size_t)row * DK  + sem * 8;   // + key0*DK per iter
  const unsigned short* VsA = Vth + (size_t)row * SEQ + sem * 8;   // + key0 per iter
  unsigned short* kd = k_sw  + wv * 512;
  unsigned short* vd = vt_sw + wv * 512;

#define STAGE(buf, key0) do {                                        \
    gld16(KsA + (size_t)(key0) * DK, kd + (buf) * 4096);             \
    gld16(VsA + (key0),              vd + (buf) * 4096);             \
  } while (0)

  // P^T exchange lanes (within the 4 quads sharing l15)
  const int srcA = l15 + ((quad & 1) << 5);
  const int srcB = srcA + 16;
  const int hi   = quad >> 1;

  // prologue: stage tile 0 into buffer 0
  STAGE(0, 0);
  __syncthreads();                         // drains vmcnt(0): tile 0 resident

  int cur = 0;
  for (int kb = 0; kb < SEQ / 64; ++kb) {
    // issue next tile's loads FIRST so they overlap this tile's compute
    if (kb + 1 < SEQ / 64) STAGE(cur ^ 1, (kb + 1) * 64);

    const unsigned short* kcur = k_sw  + cur * 4096;
    const unsigned short* vcur = vt_sw + cur * 4096;

    // S^T = K·Q^T
    f32x4 s[4];
    __builtin_amdgcn_s_setprio(1);
#pragma unroll
    for (int t = 0; t < 4; ++t) {
      const int r = t * 16 + l15;
      const int sw = (r & 7) ^ (r >> 3);
      bf16x8_t kf0 = *(const bf16x8_t*)&kcur[r * 64 + ((quad ^ sw) << 3)];
      bf16x8_t kf1 = *(const bf16x8_t*)&kcur[r * 64 + (((quad | 4) ^ sw) << 3)];
      f32x4 z = (f32x4){0.f, 0.f, 0.f, 0.f};
      z = __builtin_amdgcn_mfma_f32_16x16x32_bf16(kf0, qf0, z, 0, 0, 0);
      z = __builtin_amdgcn_mfma_f32_16x16x32_bf16(kf1, qf1, z, 0, 0, 0);
      s[t] = z;
    }
    __builtin_amdgcn_s_setprio(0);

    // online softmax, base-2 (scale folded into Q), defer-max (T13, THR=8 => P <= 2^8)
    float mx = s[0][0];
#pragma unroll
    for (int t = 0; t < 4; ++t)
#pragma unroll
      for (int r = 0; r < 4; ++r) mx = fmaxf(mx, s[t][r]);
    mx = fmaxf(mx, __shfl_xor(mx, 16));
    mx = fmaxf(mx, __shfl_xor(mx, 32));
    if (__any(mx > mval + 8.0f)) {
      const float mnew  = fmaxf(mval, mx);
      const float alpha = fexp2(mval - mnew);
      mval = mnew;
      lval *= alpha;
#pragma unroll
      for (int t = 0; t < 4; ++t) o[t] *= alpha;
    }
    // p = exp2(s - m); pack to bf16 pairs per-t so p dies early (VGPR)
    float rs = 0.f;
    unsigned int u[4][2];
#pragma unroll
    for (int t = 0; t < 4; ++t) {
      const float p0 = fexp2(s[t][0] - mval);
      const float p1 = fexp2(s[t][1] - mval);
      const float p2 = fexp2(s[t][2] - mval);
      const float p3 = fexp2(s[t][3] - mval);
      rs += (p0 + p1) + (p2 + p3);
      u[t][0] = pack2(p0, p1);
      u[t][1] = pack2(p2, p3);
    }
    rs += __shfl_xor(rs, 16);
    rs += __shfl_xor(rs, 32);
    lval += rs;

    // in-register P^T redistribution:
    // pf_c elem j = P[q=l15][key = 32c + 8*quad + j]
    //   j=0..3 from lane srcA = l15+32*(quad&1), j=4..7 from srcB = srcA+16,
    //   source t = 2c + (quad>>1), source words u[t][0..1].
    unsigned int w0[4], w1[4];
#pragma unroll
    for (int c = 0; c < 2; ++c) {
      unsigned int* wc = c ? w1 : w0;
      const unsigned int uA0 = u[2 * c][0],     uA1 = u[2 * c][1];
      const unsigned int uB0 = u[2 * c + 1][0], uB1 = u[2 * c + 1][1];
      unsigned int a, b;
      a = (unsigned int)__shfl((int)uA0, srcA); b = (unsigned int)__shfl((int)uB0, srcA);
      wc[0] = hi ? b : a;
      a = (unsigned int)__shfl((int)uA1, srcA); b = (unsigned int)__shfl((int)uB1, srcA);
      wc[1] = hi ? b : a;
      a = (unsigned int)__shfl((int)uA0, srcB); b = (unsigned int)__shfl((int)uB0, srcB);
      wc[2] = hi ? b : a;
      a = (unsigned int)__shfl((int)uA1, srcB); b = (unsigned int)__shfl((int)uB1, srcB);
      wc[3] = hi ? b : a;
    }
    union Cv { unsigned int w[4]; bf16x8_t v; };
    Cv cv0, cv1;
    cv0.w[0] = w0[0]; cv0.w[1] = w0[1]; cv0.w[2] = w0[2]; cv0.w[3] = w0[3];
    cv1.w[0] = w1[0]; cv1.w[1] = w1[1]; cv1.w[2] = w1[2]; cv1.w[3] = w1[3];
    const bf16x8_t pf0 = cv0.v;
    const bf16x8_t pf1 = cv1.v;

    // O^T += V^T · P^T
    __builtin_amdgcn_s_setprio(1);
#pragma unroll
    for (int nt = 0; nt < 4; ++nt) {
      const int r = nt * 16 + l15;
      const int sw = (r & 7) ^ (r >> 3);
      bf16x8_t vf0 = *(const bf16x8_t*)&vcur[r * 64 + ((quad ^ sw) << 3)];
      bf16x8_t vf1 = *(const bf16x8_t*)&vcur[r * 64 + (((quad | 4) ^ sw) << 3)];
      o[nt] = __builtin_amdgcn_mfma_f32_16x16x32_bf16(vf0, pf0, o[nt], 0, 0, 0);
      o[nt] = __builtin_amdgcn_mfma_f32_16x16x32_bf16(vf1, pf1, o[nt], 0, 0, 0);
    }
    __builtin_amdgcn_s_setprio(0);

    // single barrier per iter: drains this iter's prefetch (vmcnt) AND all waves' LDS reads
    __syncthreads();
    cur ^= 1;
  }
#undef STAGE

  // epilogue: lane owns q = q0+wv*16+l15, d = nt*16 + quad*4 + r
  const int bb = bh >> 4, hh = bh & 15;
  const float inv = 1.0f / lval;
  unsigned short* orow = Oattn + (size_t)(bb * SEQ + q0 + wv * 16 + l15) * D_MODEL + hh * DK + quad * 4;
#pragma unroll
  for (int nt = 0; nt < 4; ++nt) {
    f32x4 v = o[nt];
    *(uint2*)(orow + nt * 16) = make_uint2(pack2(v[0] * inv, v[1] * inv),
                                           pack2(v[2] * inv, v[3] * inv));
  }
}

extern "C" void kernel_launch(void* const* d_in, const int* in_sizes, int n_in,
                              void* d_out, int out_size, void* d_ws, size_t ws_size,
                              hipStream_t stream) {
  const float* query = (const float*)d_in[0];
  const float* key   = (const float*)d_in[1];
  const float* value = (const float*)d_in[2];
  const float* Wq    = (const float*)d_in[3];
  const float* bq    = (const float*)d_in[4];
  const float* Wk    = (const float*)d_in[5];
  const float* bk    = (const float*)d_in[6];
  const float* Wv    = (const float*)d_in[7];
  const float* bv    = (const float*)d_in[8];
  const float* Wo    = (const float*)d_in[9];
  const float* bo    = (const float*)d_in[10];

  const size_t E  = (size_t)BATCH * SEQ * D_MODEL;   // 8,388,608
  const size_t WE = (size_t)D_MODEL * D_MODEL;       // 1,048,576
  unsigned short* ws  = (unsigned short*)d_ws;
  unsigned short* Qws = ws;                          // [B,H,S,dk], pre-scaled log2e/8
  unsigned short* Kws = ws + E;
  unsigned short* Vws = ws + 2 * E;                  // [B,H,dk,S] transposed
  unsigned short* qb  = ws + 3 * E;
  unsigned short* kb  = ws + 4 * E;
  unsigned short* vb  = ws + 5 * E;
  unsigned short* wqb = ws + 6 * E;
  unsigned short* wkb = wqb + WE;
  unsigned short* wvb = wqb + 2 * WE;
  unsigned short* wob = wqb + 3 * WE;
  unsigned short* Aws = qb;                          // alias: qb dead after QKV GEMM

  cvt3_kernel<<<dim3(E / 2048, 3), 256, 0, stream>>>(query, key, value, qb, kb, vb);
  cvt4_kernel<<<dim3(WE / 2048, 4), 256, 0, stream>>>(Wq, Wk, Wv, Wo, wqb, wkb, wvb, wob);

  qkv_kernel<<<dim3(BATCH * SEQ / 128, D_MODEL / 128, 3), 256, 0, stream>>>(
      qb, kb, vb, wqb, wkb, wvb, bq, bk, bv, Qws, Kws, Vws);
  attn_kernel<<<dim3(BATCH * NHEADS, SEQ / 128), 512, 0, stream>>>(Qws, Kws, Vws, Aws);
  outproj_kernel<<<dim3(BATCH * SEQ / 128, D_MODEL / 128), 256, 0, stream>>>(
      Aws, wob, bo, (float*)d_out);
}

// Round 4
// 375.294 us; speedup vs baseline: 1.0724x; 1.0724x over previous
//
#include <hip/hip_runtime.h>
#include <hip/hip_bf16.h>
#include <cstdint>
#include <cstddef>

// MultiHeadAttention B=4, S=2048, D=1024, H=16, dk=64. fp32 in/out, bf16 MFMA internals.
// cvt fp32->bf16 -> fused QKV gemm (V written transposed [B,H,dk,S]) -> flash attn
// (512-thr, 8-wave, 256-q tile: each wave owns TWO 16-q groups so every LDS K/V fragment
//  feeds 2x MFMA -> halves DS-pipe traffic, the measured bottleneck) -> out proj.

#define BATCH   4
#define SEQ     2048
#define D_MODEL 1024
#define NHEADS  16
#define DK      64

typedef __attribute__((ext_vector_type(8))) __bf16 bf16x8_t;
typedef __attribute__((ext_vector_type(4))) float  f32x4;

// HW packed fp32->bf16 (v_cvt_pk_bf16_f32 on gfx950)
__device__ inline unsigned int pack2(float lo, float hi) {
  __hip_bfloat162 h = __float22bfloat162_rn(make_float2(lo, hi));
  union { __hip_bfloat162 h; unsigned int u; } c; c.h = h; return c.u;
}
__device__ inline unsigned short f2bf(float f) { return (unsigned short)pack2(f, f); }

#if __has_builtin(__builtin_amdgcn_exp2f)
__device__ inline float fexp2(float x) { return __builtin_amdgcn_exp2f(x); }
#else
__device__ inline float fexp2(float x) { return __expf(x * 0.6931471805599453f); }
#endif

__device__ inline void cvt8(const float* __restrict__ s, unsigned short* __restrict__ d) {
  const float4 a = *(const float4*)s;
  const float4 b = *(const float4*)(s + 4);
  uint4 r;
  r.x = pack2(a.x, a.y); r.y = pack2(a.z, a.w);
  r.z = pack2(b.x, b.y); r.w = pack2(b.z, b.w);
  *(uint4*)d = r;
}

// async global->LDS, 16B/lane; LDS dest = wave-uniform base + lane*16B
typedef __attribute__((address_space(3))) unsigned int lds_u32_t;
typedef const __attribute__((address_space(1))) unsigned int glb_u32_t;
__device__ inline void gld16(const unsigned short* g, unsigned short* l) {
  __builtin_amdgcn_global_load_lds((glb_u32_t*)(uintptr_t)g,
                                   (lds_u32_t*)(unsigned int)(uintptr_t)l, 16, 0, 0);
}

// ---------------- fp32 -> bf16 conversion ----------------
__global__ __launch_bounds__(256) void cvt3_kernel(
    const float* __restrict__ a, const float* __restrict__ b, const float* __restrict__ c,
    unsigned short* __restrict__ oa, unsigned short* __restrict__ ob, unsigned short* __restrict__ oc)
{
  const float* s = (blockIdx.y == 0) ? a : (blockIdx.y == 1) ? b : c;
  unsigned short* d = (blockIdx.y == 0) ? oa : (blockIdx.y == 1) ? ob : oc;
  const size_t i = ((size_t)blockIdx.x * 256 + threadIdx.x) * 8;
  cvt8(s + i, d + i);
}
__global__ __launch_bounds__(256) void cvt4_kernel(
    const float* __restrict__ a, const float* __restrict__ b,
    const float* __restrict__ c, const float* __restrict__ dd,
    unsigned short* __restrict__ oa, unsigned short* __restrict__ ob,
    unsigned short* __restrict__ oc, unsigned short* __restrict__ od)
{
  const float* s = (blockIdx.y == 0) ? a : (blockIdx.y == 1) ? b : (blockIdx.y == 2) ? c : dd;
  unsigned short* d = (blockIdx.y == 0) ? oa : (blockIdx.y == 1) ? ob : (blockIdx.y == 2) ? oc : od;
  const size_t i = ((size_t)blockIdx.x * 256 + threadIdx.x) * 8;
  cvt8(s + i, d + i);
}

// ---------------- shared GEMM core: acc += A[128 rows @m0] * W[128 rows @n0]^T ----------------
// m97 structure: BK=32 unpadded LDS, global_load_lds 16B, chunk^(row&3) source-side swizzle.
__device__ inline void gemm_core(const unsigned short* __restrict__ A,
                                 const unsigned short* __restrict__ W,
                                 unsigned short* a_lds, unsigned short* b_lds,
                                 int m0, int n0, f32x4 (&acc)[4][4])
{
  const int tid  = threadIdx.x;
  const int lane = tid & 63;
  const int wv   = tid >> 6;
  const int l15  = lane & 15;
  const int quad = lane >> 4;
  const int wm = (wv & 1) * 64;
  const int wn = (wv >> 1) * 64;

  const int srow = tid >> 2;
  const int sch  = (tid & 3) ^ (srow & 3);
  const unsigned short* Ap0 = A + (size_t)(m0 + srow) * D_MODEL + sch * 8;
  const unsigned short* Ap1 = Ap0 + (size_t)64 * D_MODEL;
  const unsigned short* Wp0 = W + (size_t)(n0 + srow) * D_MODEL + sch * 8;
  const unsigned short* Wp1 = Wp0 + (size_t)64 * D_MODEL;
  unsigned short* al0 = a_lds + wv * 512;
  unsigned short* al1 = a_lds + 2048 + wv * 512;
  unsigned short* bl0 = b_lds + wv * 512;
  unsigned short* bl1 = b_lds + 2048 + wv * 512;

  const int pq = (quad ^ (l15 & 3)) * 8;

  for (int k0 = 0; k0 < D_MODEL; k0 += 32) {
    __syncthreads();
    gld16(Ap0 + k0, al0);
    gld16(Ap1 + k0, al1);
    gld16(Wp0 + k0, bl0);
    gld16(Wp1 + k0, bl1);
    __syncthreads();

    bf16x8_t af[4], bfr[4];
#pragma unroll
    for (int i = 0; i < 4; ++i)
      af[i] = *(const bf16x8_t*)&a_lds[(wm + i * 16 + l15) * 32 + pq];
#pragma unroll
    for (int j = 0; j < 4; ++j)
      bfr[j] = *(const bf16x8_t*)&b_lds[(wn + j * 16 + l15) * 32 + pq];

#pragma unroll
    for (int i = 0; i < 4; ++i)
#pragma unroll
      for (int j = 0; j < 4; ++j)
        acc[i][j] = __builtin_amdgcn_mfma_f32_16x16x32_bf16(af[i], bfr[j], acc[i][j], 0, 0, 0);
  }
}

// ---------------- fused QKV projection ----------------
// grid (M/128, N/128, 3). z=0: Q (scaled log2e/8, scatter [B,H,S,dk]); z=1: K (scatter);
// z=2: V written TRANSPOSED [B,H,dk,S].
__global__ __launch_bounds__(256) void qkv_kernel(
    const unsigned short* __restrict__ qb, const unsigned short* __restrict__ kb,
    const unsigned short* __restrict__ vb,
    const unsigned short* __restrict__ wq, const unsigned short* __restrict__ wk,
    const unsigned short* __restrict__ wvp,
    const float* __restrict__ bq, const float* __restrict__ bk, const float* __restrict__ bv,
    unsigned short* __restrict__ Qws, unsigned short* __restrict__ Kws,
    unsigned short* __restrict__ Vws)
{
  __shared__ unsigned short a_lds[128 * 32];
  __shared__ unsigned short b_lds[128 * 32];

  const int z = blockIdx.z;
  const unsigned short* A = (z == 0) ? qb : (z == 1) ? kb : vb;
  const unsigned short* W = (z == 0) ? wq : (z == 1) ? wk : wvp;
  const float* bias       = (z == 0) ? bq : (z == 1) ? bk : bv;
  unsigned short* C       = (z == 0) ? Qws : (z == 1) ? Kws : Vws;
  const int m0 = blockIdx.x * 128;
  const int n0 = blockIdx.y * 128;

  f32x4 acc[4][4];
#pragma unroll
  for (int i = 0; i < 4; ++i)
#pragma unroll
    for (int j = 0; j < 4; ++j)
      acc[i][j] = (f32x4){0.f, 0.f, 0.f, 0.f};

  gemm_core(A, W, a_lds, b_lds, m0, n0, acc);

  const int tid  = threadIdx.x;
  const int lane = tid & 63;
  const int wv   = tid >> 6;
  const int l15  = lane & 15;
  const int quad = lane >> 4;
  const int wm = (wv & 1) * 64;
  const int wn = (wv >> 1) * 64;
  // C/D layout: col = lane&15, row = quad*4 + reg  [m89]
  if (z == 2) {
    // V^T: off = ((bb*H+hh)*DK+dd)*SEQ + ss; 4 consecutive ss per lane -> uint2
    for (int j = 0; j < 4; ++j) {
      const int n = n0 + wn + j * 16 + l15;
      const int hh = n >> 6, dd = n & 63;
      const float bvl = bias[n];
      for (int i = 0; i < 4; ++i) {
        const int mbase = m0 + wm + i * 16 + quad * 4;
        const int bb = mbase >> 11, ss = mbase & 2047;
        uint2 w2 = make_uint2(pack2(acc[i][j][0] + bvl, acc[i][j][1] + bvl),
                              pack2(acc[i][j][2] + bvl, acc[i][j][3] + bvl));
        *(uint2*)(C + (((size_t)bb * NHEADS + hh) * DK + dd) * SEQ + ss) = w2;
      }
    }
  } else {
    const float oscale = (z == 0) ? 0.18033688011112042f : 1.0f;  // log2(e)/8 for Q
    for (int j = 0; j < 4; ++j) {
      const int n = n0 + wn + j * 16 + l15;
      const int hh = n >> 6, dd = n & 63;
      const float bvl = bias[n];
      for (int i = 0; i < 4; ++i) {
        const int mbase = m0 + wm + i * 16 + quad * 4;
        const int bb = mbase >> 11, ss = mbase & 2047;
        unsigned short* dst = C + (((size_t)bb * NHEADS + hh) * SEQ + ss) * DK + dd;
        for (int r = 0; r < 4; ++r)
          dst[(size_t)r * DK] = f2bf((acc[i][j][r] + bvl) * oscale);
      }
    }
  }
}

// ---------------- output projection (bf16 A, fp32 out) ----------------
__global__ __launch_bounds__(256) void outproj_kernel(
    const unsigned short* __restrict__ A, const unsigned short* __restrict__ W,
    const float* __restrict__ bias, float* __restrict__ C)
{
  __shared__ unsigned short a_lds[128 * 32];
  __shared__ unsigned short b_lds[128 * 32];
  const int m0 = blockIdx.x * 128;
  const int n0 = blockIdx.y * 128;

  f32x4 acc[4][4];
#pragma unroll
  for (int i = 0; i < 4; ++i)
#pragma unroll
    for (int j = 0; j < 4; ++j)
      acc[i][j] = (f32x4){0.f, 0.f, 0.f, 0.f};

  gemm_core(A, W, a_lds, b_lds, m0, n0, acc);

  const int tid  = threadIdx.x;
  const int lane = tid & 63;
  const int wv   = tid >> 6;
  const int l15  = lane & 15;
  const int quad = lane >> 4;
  const int wm = (wv & 1) * 64;
  const int wn = (wv >> 1) * 64;
  for (int j = 0; j < 4; ++j) {
    const int n = n0 + wn + j * 16 + l15;
    const float bvl = bias[n];
    for (int i = 0; i < 4; ++i) {
      const int mbase = m0 + wm + i * 16 + quad * 4;
      for (int r = 0; r < 4; ++r)
        C[(size_t)(mbase + r) * D_MODEL + n] = acc[i][j][r] + bvl;
    }
  }
}

// in-register P^T redistribution (quads sharing l15):
// pf_c elem j = P[q=l15][key = 32c + 8*quad + j]; j=0..3 from lane srcA, j=4..7 from srcB,
// source t = 2c + (quad>>1), source words u[t][0..1].
__device__ inline void exchP(const unsigned int (&u)[4][2], int srcA, int srcB, int hi,
                             bf16x8_t& pf0, bf16x8_t& pf1)
{
  unsigned int w0[4], w1[4];
#pragma unroll
  for (int c = 0; c < 2; ++c) {
    unsigned int* wc = c ? w1 : w0;
    const unsigned int uA0 = u[2 * c][0],     uA1 = u[2 * c][1];
    const unsigned int uB0 = u[2 * c + 1][0], uB1 = u[2 * c + 1][1];
    unsigned int a, b;
    a = (unsigned int)__shfl((int)uA0, srcA); b = (unsigned int)__shfl((int)uB0, srcA);
    wc[0] = hi ? b : a;
    a = (unsigned int)__shfl((int)uA1, srcA); b = (unsigned int)__shfl((int)uB1, srcA);
    wc[1] = hi ? b : a;
    a = (unsigned int)__shfl((int)uA0, srcB); b = (unsigned int)__shfl((int)uB0, srcB);
    wc[2] = hi ? b : a;
    a = (unsigned int)__shfl((int)uA1, srcB); b = (unsigned int)__shfl((int)uB1, srcB);
    wc[3] = hi ? b : a;
  }
  union Cv { unsigned int w[4]; bf16x8_t v; };
  Cv cv0, cv1;
  cv0.w[0] = w0[0]; cv0.w[1] = w0[1]; cv0.w[2] = w0[2]; cv0.w[3] = w0[3];
  cv1.w[0] = w1[0]; cv1.w[1] = w1[1]; cv1.w[2] = w1[2]; cv1.w[3] = w1[3];
  pf0 = cv0.v;
  pf1 = cv1.v;
}

// ---------------- Flash attention, S^T form, 2 q-groups per wave ----------------
// 512 thr (8 waves), Q-tile 256 rows; grid (B*H, S/256). Wave wv owns q-rows
// {q0+wv*16+l15} (group A) and {q0+128+wv*16+l15} (group B). Each K/V LDS fragment
// is read ONCE and feeds both groups' MFMAs -> LDS-read bytes per FLOP halved
// (DS pipe was the measured invariant bottleneck across R0-R3).
// K/V^T DMA-staged double-buffered; per-lane softmax (base-2, Q pre-scaled log2e/8,
// defer-max THR=8); in-register P^T exchange; O^T = V^T*P^T. 32 KiB LDS.
__global__ __launch_bounds__(512, 4) void attn_kernel(
    const unsigned short* __restrict__ Q,    // [B,H,S,dk]
    const unsigned short* __restrict__ K,    // [B,H,S,dk]
    const unsigned short* __restrict__ Vt,   // [B,H,dk,S]  (pre-transposed)
    unsigned short* __restrict__ Oattn)      // [B,S,D]
{
  __shared__ unsigned short k_sw[2 * 64 * 64];
  __shared__ unsigned short vt_sw[2 * 64 * 64];

  const int tid  = threadIdx.x;
  const int lane = tid & 63;
  const int wv   = tid >> 6;              // 0..7
  const int l15  = lane & 15;
  const int quad = lane >> 4;
  const int bh   = blockIdx.x;            // bh-major: XCD = bh%8 -> K/V L2 locality
  const int q0   = blockIdx.y * 256;
  const size_t hoff = (size_t)bh * SEQ * DK;
  const unsigned short* Qh  = Q  + hoff;
  const unsigned short* Kh  = K  + hoff;
  const unsigned short* Vth = Vt + hoff;

  bf16x8_t qfA0, qfA1, qfB0, qfB1;
  {
    const unsigned short* qrA = Qh + (size_t)(q0 + wv * 16 + l15) * DK;
    const unsigned short* qrB = qrA + (size_t)128 * DK;
    qfA0 = *(const bf16x8_t*)(qrA + quad * 8);
    qfA1 = *(const bf16x8_t*)(qrA + 32 + quad * 8);
    qfB0 = *(const bf16x8_t*)(qrB + quad * 8);
    qfB1 = *(const bf16x8_t*)(qrB + 32 + quad * 8);
  }

  f32x4 oA[4], oB[4];
#pragma unroll
  for (int t = 0; t < 4; ++t) {
    oA[t] = (f32x4){0.f, 0.f, 0.f, 0.f};
    oB[t] = (f32x4){0.f, 0.f, 0.f, 0.f};
  }
  float mA = -1e30f, lA = 0.f;
  float mB = -1e30f, lB = 0.f;

  // DMA staging: wave wv covers tile rows [wv*8, wv*8+8) of K and of V^T (1 gld16 each).
  const int sr  = lane >> 3;              // 0..7 (row within the wave's 8-row slab)
  const int pc  = lane & 7;               // phys chunk
  const int row = wv * 8 + sr;
  const int sem = pc ^ sr ^ wv;           // (row&7)=sr, (row>>3)=wv
  const unsigned short* KsA = Kh  + (size_t)row * DK  + sem * 8;   // + key0*DK per iter
  const unsigned short* VsA = Vth + (size_t)row * SEQ + sem * 8;   // + key0 per iter
  unsigned short* kd = k_sw  + wv * 512;
  unsigned short* vd = vt_sw + wv * 512;

#define STAGE(buf, key0) do {                                        \
    gld16(KsA + (size_t)(key0) * DK, kd + (buf) * 4096);             \
    gld16(VsA + (key0),              vd + (buf) * 4096);             \
  } while (0)

  // P^T exchange lanes (within the 4 quads sharing l15)
  const int srcA = l15 + ((quad & 1) << 5);
  const int srcB = srcA + 16;
  const int hi   = quad >> 1;

  // prologue: stage tile 0 into buffer 0
  STAGE(0, 0);
  __syncthreads();                         // drains vmcnt(0): tile 0 resident

  int cur = 0;
  for (int kb = 0; kb < SEQ / 64; ++kb) {
    // issue next tile's loads FIRST so they overlap this tile's compute
    if (kb + 1 < SEQ / 64) STAGE(cur ^ 1, (kb + 1) * 64);

    const unsigned short* kcur = k_sw  + cur * 4096;
    const unsigned short* vcur = vt_sw + cur * 4096;

    // S^T = K·Q^T for both q-groups; each kf fragment read once, used twice
    f32x4 sA[4], sB[4];
    __builtin_amdgcn_s_setprio(1);
#pragma unroll
    for (int t = 0; t < 4; ++t) {
      const int r = t * 16 + l15;
      const int sw = (r & 7) ^ (r >> 3);
      bf16x8_t kf0 = *(const bf16x8_t*)&kcur[r * 64 + ((quad ^ sw) << 3)];
      bf16x8_t kf1 = *(const bf16x8_t*)&kcur[r * 64 + (((quad | 4) ^ sw) << 3)];
      f32x4 zA = (f32x4){0.f, 0.f, 0.f, 0.f};
      zA = __builtin_amdgcn_mfma_f32_16x16x32_bf16(kf0, qfA0, zA, 0, 0, 0);
      zA = __builtin_amdgcn_mfma_f32_16x16x32_bf16(kf1, qfA1, zA, 0, 0, 0);
      sA[t] = zA;
      f32x4 zB = (f32x4){0.f, 0.f, 0.f, 0.f};
      zB = __builtin_amdgcn_mfma_f32_16x16x32_bf16(kf0, qfB0, zB, 0, 0, 0);
      zB = __builtin_amdgcn_mfma_f32_16x16x32_bf16(kf1, qfB1, zB, 0, 0, 0);
      sB[t] = zB;
    }
    __builtin_amdgcn_s_setprio(0);

    // online softmax group A (base-2; defer-max THR=8 => P <= 2^8)
    bf16x8_t pfA0, pfA1, pfB0, pfB1;
    {
      float mx = sA[0][0];
#pragma unroll
      for (int t = 0; t < 4; ++t)
#pragma unroll
        for (int r = 0; r < 4; ++r) mx = fmaxf(mx, sA[t][r]);
      mx = fmaxf(mx, __shfl_xor(mx, 16));
      mx = fmaxf(mx, __shfl_xor(mx, 32));
      if (__any(mx > mA + 8.0f)) {
        const float mnew  = fmaxf(mA, mx);
        const float alpha = fexp2(mA - mnew);
        mA = mnew;
        lA *= alpha;
#pragma unroll
        for (int t = 0; t < 4; ++t) oA[t] *= alpha;
      }
      float rs = 0.f;
      unsigned int u[4][2];
#pragma unroll
      for (int t = 0; t < 4; ++t) {
        const float p0 = fexp2(sA[t][0] - mA);
        const float p1 = fexp2(sA[t][1] - mA);
        const float p2 = fexp2(sA[t][2] - mA);
        const float p3 = fexp2(sA[t][3] - mA);
        rs += (p0 + p1) + (p2 + p3);
        u[t][0] = pack2(p0, p1);
        u[t][1] = pack2(p2, p3);
      }
      rs += __shfl_xor(rs, 16);
      rs += __shfl_xor(rs, 32);
      lA += rs;
      exchP(u, srcA, srcB, hi, pfA0, pfA1);
    }
    // online softmax group B
    {
      float mx = sB[0][0];
#pragma unroll
      for (int t = 0; t < 4; ++t)
#pragma unroll
        for (int r = 0; r < 4; ++r) mx = fmaxf(mx, sB[t][r]);
      mx = fmaxf(mx, __shfl_xor(mx, 16));
      mx = fmaxf(mx, __shfl_xor(mx, 32));
      if (__any(mx > mB + 8.0f)) {
        const float mnew  = fmaxf(mB, mx);
        const float alpha = fexp2(mB - mnew);
        mB = mnew;
        lB *= alpha;
#pragma unroll
        for (int t = 0; t < 4; ++t) oB[t] *= alpha;
      }
      float rs = 0.f;
      unsigned int u[4][2];
#pragma unroll
      for (int t = 0; t < 4; ++t) {
        const float p0 = fexp2(sB[t][0] - mB);
        const float p1 = fexp2(sB[t][1] - mB);
        const float p2 = fexp2(sB[t][2] - mB);
        const float p3 = fexp2(sB[t][3] - mB);
        rs += (p0 + p1) + (p2 + p3);
        u[t][0] = pack2(p0, p1);
        u[t][1] = pack2(p2, p3);
      }
      rs += __shfl_xor(rs, 16);
      rs += __shfl_xor(rs, 32);
      lB += rs;
      exchP(u, srcA, srcB, hi, pfB0, pfB1);
    }

    // O^T += V^T · P^T; each vf fragment read once, used twice
    __builtin_amdgcn_s_setprio(1);
#pragma unroll
    for (int nt = 0; nt < 4; ++nt) {
      const int r = nt * 16 + l15;
      const int sw = (r & 7) ^ (r >> 3);
      bf16x8_t vf0 = *(const bf16x8_t*)&vcur[r * 64 + ((quad ^ sw) << 3)];
      bf16x8_t vf1 = *(const bf16x8_t*)&vcur[r * 64 + (((quad | 4) ^ sw) << 3)];
      oA[nt] = __builtin_amdgcn_mfma_f32_16x16x32_bf16(vf0, pfA0, oA[nt], 0, 0, 0);
      oA[nt] = __builtin_amdgcn_mfma_f32_16x16x32_bf16(vf1, pfA1, oA[nt], 0, 0, 0);
      oB[nt] = __builtin_amdgcn_mfma_f32_16x16x32_bf16(vf0, pfB0, oB[nt], 0, 0, 0);
      oB[nt] = __builtin_amdgcn_mfma_f32_16x16x32_bf16(vf1, pfB1, oB[nt], 0, 0, 0);
    }
    __builtin_amdgcn_s_setprio(0);

    // single barrier per iter: drains this iter's prefetch (vmcnt) AND all waves' LDS reads
    __syncthreads();
    cur ^= 1;
  }
#undef STAGE

  // epilogue: group A q = q0+wv*16+l15, group B q = +128; d = nt*16 + quad*4 + r
  const int bb = bh >> 4, hh = bh & 15;
  {
    const float inv = 1.0f / lA;
    unsigned short* orow = Oattn + (size_t)(bb * SEQ + q0 + wv * 16 + l15) * D_MODEL + hh * DK + quad * 4;
#pragma unroll
    for (int nt = 0; nt < 4; ++nt) {
      f32x4 v = oA[nt];
      *(uint2*)(orow + nt * 16) = make_uint2(pack2(v[0] * inv, v[1] * inv),
                                             pack2(v[2] * inv, v[3] * inv));
    }
  }
  {
    const float inv = 1.0f / lB;
    unsigned short* orow = Oattn + (size_t)(bb * SEQ + q0 + 128 + wv * 16 + l15) * D_MODEL + hh * DK + quad * 4;
#pragma unroll
    for (int nt = 0; nt < 4; ++nt) {
      f32x4 v = oB[nt];
      *(uint2*)(orow + nt * 16) = make_uint2(pack2(v[0] * inv, v[1] * inv),
                                             pack2(v[2] * inv, v[3] * inv));
    }
  }
}

extern "C" void kernel_launch(void* const* d_in, const int* in_sizes, int n_in,
                              void* d_out, int out_size, void* d_ws, size_t ws_size,
                              hipStream_t stream) {
  const float* query = (const float*)d_in[0];
  const float* key   = (const float*)d_in[1];
  const float* value = (const float*)d_in[2];
  const float* Wq    = (const float*)d_in[3];
  const float* bq    = (const float*)d_in[4];
  const float* Wk    = (const float*)d_in[5];
  const float* bk    = (const float*)d_in[6];
  const float* Wv    = (const float*)d_in[7];
  const float* bv    = (const float*)d_in[8];
  const float* Wo    = (const float*)d_in[9];
  const float* bo    = (const float*)d_in[10];

  const size_t E  = (size_t)BATCH * SEQ * D_MODEL;   // 8,388,608
  const size_t WE = (size_t)D_MODEL * D_MODEL;       // 1,048,576
  unsigned short* ws  = (unsigned short*)d_ws;
  unsigned short* Qws = ws;                          // [B,H,S,dk], pre-scaled log2e/8
  unsigned short* Kws = ws + E;
  unsigned short* Vws = ws + 2 * E;                  // [B,H,dk,S] transposed
  unsigned short* qb  = ws + 3 * E;
  unsigned short* kb  = ws + 4 * E;
  unsigned short* vb  = ws + 5 * E;
  unsigned short* wqb = ws + 6 * E;
  unsigned short* wkb = wqb + WE;
  unsigned short* wvb = wqb + 2 * WE;
  unsigned short* wob = wqb + 3 * WE;
  unsigned short* Aws = qb;                          // alias: qb dead after QKV GEMM

  cvt3_kernel<<<dim3(E / 2048, 3), 256, 0, stream>>>(query, key, value, qb, kb, vb);
  cvt4_kernel<<<dim3(WE / 2048, 4), 256, 0, stream>>>(Wq, Wk, Wv, Wo, wqb, wkb, wvb, wob);

  qkv_kernel<<<dim3(BATCH * SEQ / 128, D_MODEL / 128, 3), 256, 0, stream>>>(
      qb, kb, vb, wqb, wkb, wvb, bq, bk, bv, Qws, Kws, Vws);
  attn_kernel<<<dim3(BATCH * NHEADS, SEQ / 256), 512, 0, stream>>>(Qws, Kws, Vws, Aws);
  outproj_kernel<<<dim3(BATCH * SEQ / 128, D_MODEL / 128), 256, 0, stream>>>(
      Aws, wob, bo, (float*)d_out);
}

// Round 7
// 365.377 us; speedup vs baseline: 1.1015x; 1.0271x over previous
//
#include <hip/hip_runtime.h>
#include <hip/hip_bf16.h>
#include <cstdint>
#include <cstddef>

// MultiHeadAttention B=4, S=2048, D=1024, H=16, dk=64. fp32 in/out, bf16 MFMA internals.
// cvt fp32->bf16 -> fused QKV gemm (V written transposed [B,H,dk,S]) -> flash attn
// (512-thr, 8 waves x 32q, 32x32x16 MFMA swapped-operand form; softmax per-lane;
//  cross-half exchange via verified __shfl_xor(.,32) -- permlane32_swap dropped after
//  two failed semantic guesses R5/R6) -> out proj.

#define BATCH   4
#define SEQ     2048
#define D_MODEL 1024
#define NHEADS  16
#define DK      64

typedef __attribute__((ext_vector_type(8)))  __bf16 bf16x8_t;
typedef __attribute__((ext_vector_type(4)))  float  f32x4;
typedef __attribute__((ext_vector_type(16))) float  f32x16;

// HW packed fp32->bf16 (v_cvt_pk_bf16_f32 on gfx950)
__device__ inline unsigned int pack2(float lo, float hi) {
  __hip_bfloat162 h = __float22bfloat162_rn(make_float2(lo, hi));
  union { __hip_bfloat162 h; unsigned int u; } c; c.h = h; return c.u;
}
__device__ inline unsigned short f2bf(float f) { return (unsigned short)pack2(f, f); }

#if __has_builtin(__builtin_amdgcn_exp2f)
__device__ inline float fexp2(float x) { return __builtin_amdgcn_exp2f(x); }
#else
__device__ inline float fexp2(float x) { return __expf(x * 0.6931471805599453f); }
#endif

__device__ inline unsigned int exch32(unsigned int x) {  // partner lane^32 (verified prim)
  return (unsigned int)__shfl_xor((int)x, 32);
}

__device__ inline void cvt8(const float* __restrict__ s, unsigned short* __restrict__ d) {
  const float4 a = *(const float4*)s;
  const float4 b = *(const float4*)(s + 4);
  uint4 r;
  r.x = pack2(a.x, a.y); r.y = pack2(a.z, a.w);
  r.z = pack2(b.x, b.y); r.w = pack2(b.z, b.w);
  *(uint4*)d = r;
}

// async global->LDS, 16B/lane; LDS dest = wave-uniform base + lane*16B
typedef __attribute__((address_space(3))) unsigned int lds_u32_t;
typedef const __attribute__((address_space(1))) unsigned int glb_u32_t;
__device__ inline void gld16(const unsigned short* g, unsigned short* l) {
  __builtin_amdgcn_global_load_lds((glb_u32_t*)(uintptr_t)g,
                                   (lds_u32_t*)(unsigned int)(uintptr_t)l, 16, 0, 0);
}

// ---------------- fp32 -> bf16 conversion ----------------
__global__ __launch_bounds__(256) void cvt3_kernel(
    const float* __restrict__ a, const float* __restrict__ b, const float* __restrict__ c,
    unsigned short* __restrict__ oa, unsigned short* __restrict__ ob, unsigned short* __restrict__ oc)
{
  const float* s = (blockIdx.y == 0) ? a : (blockIdx.y == 1) ? b : c;
  unsigned short* d = (blockIdx.y == 0) ? oa : (blockIdx.y == 1) ? ob : oc;
  const size_t i = ((size_t)blockIdx.x * 256 + threadIdx.x) * 8;
  cvt8(s + i, d + i);
}
__global__ __launch_bounds__(256) void cvt4_kernel(
    const float* __restrict__ a, const float* __restrict__ b,
    const float* __restrict__ c, const float* __restrict__ dd,
    unsigned short* __restrict__ oa, unsigned short* __restrict__ ob,
    unsigned short* __restrict__ oc, unsigned short* __restrict__ od)
{
  const float* s = (blockIdx.y == 0) ? a : (blockIdx.y == 1) ? b : (blockIdx.y == 2) ? c : dd;
  unsigned short* d = (blockIdx.y == 0) ? oa : (blockIdx.y == 1) ? ob : (blockIdx.y == 2) ? oc : od;
  const size_t i = ((size_t)blockIdx.x * 256 + threadIdx.x) * 8;
  cvt8(s + i, d + i);
}

// ---------------- shared GEMM core: acc += A[128 rows @m0] * W[128 rows @n0]^T ----------------
// m97 structure: BK=32 unpadded LDS, global_load_lds 16B, chunk^(row&3) source-side swizzle.
__device__ inline void gemm_core(const unsigned short* __restrict__ A,
                                 const unsigned short* __restrict__ W,
                                 unsigned short* a_lds, unsigned short* b_lds,
                                 int m0, int n0, f32x4 (&acc)[4][4])
{
  const int tid  = threadIdx.x;
  const int lane = tid & 63;
  const int wv   = tid >> 6;
  const int l15  = lane & 15;
  const int quad = lane >> 4;
  const int wm = (wv & 1) * 64;
  const int wn = (wv >> 1) * 64;

  const int srow = tid >> 2;
  const int sch  = (tid & 3) ^ (srow & 3);
  const unsigned short* Ap0 = A + (size_t)(m0 + srow) * D_MODEL + sch * 8;
  const unsigned short* Ap1 = Ap0 + (size_t)64 * D_MODEL;
  const unsigned short* Wp0 = W + (size_t)(n0 + srow) * D_MODEL + sch * 8;
  const unsigned short* Wp1 = Wp0 + (size_t)64 * D_MODEL;
  unsigned short* al0 = a_lds + wv * 512;
  unsigned short* al1 = a_lds + 2048 + wv * 512;
  unsigned short* bl0 = b_lds + wv * 512;
  unsigned short* bl1 = b_lds + 2048 + wv * 512;

  const int pq = (quad ^ (l15 & 3)) * 8;

  for (int k0 = 0; k0 < D_MODEL; k0 += 32) {
    __syncthreads();
    gld16(Ap0 + k0, al0);
    gld16(Ap1 + k0, al1);
    gld16(Wp0 + k0, bl0);
    gld16(Wp1 + k0, bl1);
    __syncthreads();

    bf16x8_t af[4], bfr[4];
#pragma unroll
    for (int i = 0; i < 4; ++i)
      af[i] = *(const bf16x8_t*)&a_lds[(wm + i * 16 + l15) * 32 + pq];
#pragma unroll
    for (int j = 0; j < 4; ++j)
      bfr[j] = *(const bf16x8_t*)&b_lds[(wn + j * 16 + l15) * 32 + pq];

#pragma unroll
    for (int i = 0; i < 4; ++i)
#pragma unroll
      for (int j = 0; j < 4; ++j)
        acc[i][j] = __builtin_amdgcn_mfma_f32_16x16x32_bf16(af[i], bfr[j], acc[i][j], 0, 0, 0);
  }
}

// ---------------- fused QKV projection ----------------
// grid (M/128, N/128, 3). z=0: Q (scaled log2e/8, scatter [B,H,S,dk]); z=1: K (scatter);
// z=2: V written TRANSPOSED [B,H,dk,S].
__global__ __launch_bounds__(256) void qkv_kernel(
    const unsigned short* __restrict__ qb, const unsigned short* __restrict__ kb,
    const unsigned short* __restrict__ vb,
    const unsigned short* __restrict__ wq, const unsigned short* __restrict__ wk,
    const unsigned short* __restrict__ wvp,
    const float* __restrict__ bq, const float* __restrict__ bk, const float* __restrict__ bv,
    unsigned short* __restrict__ Qws, unsigned short* __restrict__ Kws,
    unsigned short* __restrict__ Vws)
{
  __shared__ unsigned short a_lds[128 * 32];
  __shared__ unsigned short b_lds[128 * 32];

  const int z = blockIdx.z;
  const unsigned short* A = (z == 0) ? qb : (z == 1) ? kb : vb;
  const unsigned short* W = (z == 0) ? wq : (z == 1) ? wk : wvp;
  const float* bias       = (z == 0) ? bq : (z == 1) ? bk : bv;
  unsigned short* C       = (z == 0) ? Qws : (z == 1) ? Kws : Vws;
  const int m0 = blockIdx.x * 128;
  const int n0 = blockIdx.y * 128;

  f32x4 acc[4][4];
#pragma unroll
  for (int i = 0; i < 4; ++i)
#pragma unroll
    for (int j = 0; j < 4; ++j)
      acc[i][j] = (f32x4){0.f, 0.f, 0.f, 0.f};

  gemm_core(A, W, a_lds, b_lds, m0, n0, acc);

  const int tid  = threadIdx.x;
  const int lane = tid & 63;
  const int wv   = tid >> 6;
  const int l15  = lane & 15;
  const int quad = lane >> 4;
  const int wm = (wv & 1) * 64;
  const int wn = (wv >> 1) * 64;
  // C/D layout: col = lane&15, row = quad*4 + reg  [m89]
  if (z == 2) {
    // V^T: off = ((bb*H+hh)*DK+dd)*SEQ + ss; 4 consecutive ss per lane -> uint2
    for (int j = 0; j < 4; ++j) {
      const int n = n0 + wn + j * 16 + l15;
      const int hh = n >> 6, dd = n & 63;
      const float bvl = bias[n];
      for (int i = 0; i < 4; ++i) {
        const int mbase = m0 + wm + i * 16 + quad * 4;
        const int bb = mbase >> 11, ss = mbase & 2047;
        uint2 w2 = make_uint2(pack2(acc[i][j][0] + bvl, acc[i][j][1] + bvl),
                              pack2(acc[i][j][2] + bvl, acc[i][j][3] + bvl));
        *(uint2*)(C + (((size_t)bb * NHEADS + hh) * DK + dd) * SEQ + ss) = w2;
      }
    }
  } else {
    const float oscale = (z == 0) ? 0.18033688011112042f : 1.0f;  // log2(e)/8 for Q
    for (int j = 0; j < 4; ++j) {
      const int n = n0 + wn + j * 16 + l15;
      const int hh = n >> 6, dd = n & 63;
      const float bvl = bias[n];
      for (int i = 0; i < 4; ++i) {
        const int mbase = m0 + wm + i * 16 + quad * 4;
        const int bb = mbase >> 11, ss = mbase & 2047;
        unsigned short* dst = C + (((size_t)bb * NHEADS + hh) * SEQ + ss) * DK + dd;
        for (int r = 0; r < 4; ++r)
          dst[(size_t)r * DK] = f2bf((acc[i][j][r] + bvl) * oscale);
      }
    }
  }
}

// ---------------- output projection (bf16 A, fp32 out) ----------------
__global__ __launch_bounds__(256) void outproj_kernel(
    const unsigned short* __restrict__ A, const unsigned short* __restrict__ W,
    const float* __restrict__ bias, float* __restrict__ C)
{
  __shared__ unsigned short a_lds[128 * 32];
  __shared__ unsigned short b_lds[128 * 32];
  const int m0 = blockIdx.x * 128;
  const int n0 = blockIdx.y * 128;

  f32x4 acc[4][4];
#pragma unroll
  for (int i = 0; i < 4; ++i)
#pragma unroll
    for (int j = 0; j < 4; ++j)
      acc[i][j] = (f32x4){0.f, 0.f, 0.f, 0.f};

  gemm_core(A, W, a_lds, b_lds, m0, n0, acc);

  const int tid  = threadIdx.x;
  const int lane = tid & 63;
  const int wv   = tid >> 6;
  const int l15  = lane & 15;
  const int quad = lane >> 4;
  const int wm = (wv & 1) * 64;
  const int wn = (wv >> 1) * 64;
  for (int j = 0; j < 4; ++j) {
    const int n = n0 + wn + j * 16 + l15;
    const float bvl = bias[n];
    for (int i = 0; i < 4; ++i) {
      const int mbase = m0 + wm + i * 16 + quad * 4;
      for (int r = 0; r < 4; ++r)
        C[(size_t)(mbase + r) * D_MODEL + n] = acc[i][j][r] + bvl;
    }
  }
}

// ---------------- Flash attention, swapped 32x32x16 form ----------------
// 512 thr (8 waves), wave wv owns 32 q-rows (q0 + wv*32 + l31); grid (B*H, S/256).
// S^T[64k x 32q] = K·Q^T via 2 key-slices x 4 dk-slices of mfma_32x32x16.
//   C/D: col = lane&31 = q, row = (reg&3)+8*(reg>>2)+4*(lane>>5)  [m74/m101]
// Lane holds 32 of 64 key-scores for its q (hb=0: keys {0-3,8-11,16-19,24-27}(+32),
// hb=1: +4); partner (lane^32) holds the rest. Cross-half combines + P^T B-fragment
// build use __shfl_xor(.,32) (verified primitive).
// Word map (w[m] = pack(reg 2m, 2m+1)): w[0..3] = key pairs {4hb,4hb+1},{4hb+2,4hb+3},
// {8+4hb,...},{8+4hb+2,...}; w[4..7] same +16. B-frag word W needs keys 16t+hb*8+2W:
//   pf.W0 = hb ? ex(w[2]) : w[0];  pf.W1 = hb ? ex(w[3]) : w[1];
//   pf.W2 = hb ? w[2] : ex(w[0]);  pf.W3 = hb ? w[3] : ex(w[1]);
// K/V^T DMA-staged double-buffered, source-side XOR swizzle chunk^(row&7)^(row>>3).
__global__ __launch_bounds__(512, 4) void attn_kernel(
    const unsigned short* __restrict__ Q,    // [B,H,S,dk]
    const unsigned short* __restrict__ K,    // [B,H,S,dk]
    const unsigned short* __restrict__ Vt,   // [B,H,dk,S]  (pre-transposed)
    unsigned short* __restrict__ Oattn)      // [B,S,D]
{
  __shared__ unsigned short k_sw[2 * 64 * 64];
  __shared__ unsigned short vt_sw[2 * 64 * 64];

  const int tid  = threadIdx.x;
  const int lane = tid & 63;
  const int wv   = tid >> 6;              // 0..7
  const int l31  = lane & 31;
  const int hb   = lane >> 5;             // half index
  const int bh   = blockIdx.x;            // bh-major: XCD = bh%8 -> K/V L2 locality
  const int q0   = blockIdx.y * 256;
  const size_t hoff = (size_t)bh * SEQ * DK;
  const unsigned short* Qh  = Q  + hoff;
  const unsigned short* Kh  = K  + hoff;
  const unsigned short* Vth = Vt + hoff;

  // Q fragments: q = q0 + wv*32 + l31, dk = kk*16 + hb*8 + j
  bf16x8_t qf[4];
  {
    const unsigned short* qr = Qh + (size_t)(q0 + wv * 32 + l31) * DK;
#pragma unroll
    for (int kk = 0; kk < 4; ++kk)
      qf[kk] = *(const bf16x8_t*)(qr + kk * 16 + hb * 8);
  }

  f32x16 oAcc[2];
#pragma unroll
  for (int dh = 0; dh < 2; ++dh)
#pragma unroll
    for (int i = 0; i < 16; ++i) oAcc[dh][i] = 0.f;
  float mval = -1e30f, lval = 0.f;

  // DMA staging: wave wv covers tile rows [wv*8, wv*8+8) of K and of V^T (1 gld16 each).
  const int sr  = lane >> 3;              // 0..7 (row within the wave's 8-row slab)
  const int pc  = lane & 7;               // phys chunk
  const int row = wv * 8 + sr;
  const int sem = pc ^ sr ^ wv;           // (row&7)=sr, (row>>3)=wv
  const unsigned short* KsA = Kh  + (size_t)row * DK  + sem * 8;   // + key0*DK per iter
  const unsigned short* VsA = Vth + (size_t)row * SEQ + sem * 8;   // + key0 per iter
  unsigned short* kd = k_sw  + wv * 512;
  unsigned short* vd = vt_sw + wv * 512;

#define STAGE(buf, key0) do {                                        \
    gld16(KsA + (size_t)(key0) * DK, kd + (buf) * 4096);             \
    gld16(VsA + (key0),              vd + (buf) * 4096);             \
  } while (0)

  // prologue: stage tile 0 into buffer 0
  STAGE(0, 0);
  __syncthreads();                         // drains vmcnt(0): tile 0 resident

  const int swr0 = (l31 & 7) ^ (l31 >> 3);         // swizzle for rows l31      (slice 0)
  const int swr1 = (l31 & 7) ^ ((l31 >> 3) ^ 4);   // swizzle for rows 32+l31   (slice 1)

  int cur = 0;
  for (int kb = 0; kb < SEQ / 64; ++kb) {
    // issue next tile's loads FIRST so they overlap this tile's compute
    if (kb + 1 < SEQ / 64) STAGE(cur ^ 1, (kb + 1) * 64);

    const unsigned short* kcur = k_sw  + cur * 4096;
    const unsigned short* vcur = vt_sw + cur * 4096;

    // S^T = K·Q^T : s0 = keys 0..31 rows, s1 = keys 32..63 rows (per C/D row map)
    f32x16 s0, s1;
#pragma unroll
    for (int i = 0; i < 16; ++i) { s0[i] = 0.f; s1[i] = 0.f; }
    __builtin_amdgcn_s_setprio(1);
    {
      const unsigned short* krow = kcur + l31 * 64;
#pragma unroll
      for (int kk = 0; kk < 4; ++kk) {
        bf16x8_t kf = *(const bf16x8_t*)&krow[((2 * kk + hb) ^ swr0) << 3];
        s0 = __builtin_amdgcn_mfma_f32_32x32x16_bf16(kf, qf[kk], s0, 0, 0, 0);
      }
    }
    {
      const unsigned short* krow = kcur + (32 + l31) * 64;
#pragma unroll
      for (int kk = 0; kk < 4; ++kk) {
        bf16x8_t kf = *(const bf16x8_t*)&krow[((2 * kk + hb) ^ swr1) << 3];
        s1 = __builtin_amdgcn_mfma_f32_32x32x16_bf16(kf, qf[kk], s1, 0, 0, 0);
      }
    }
    __builtin_amdgcn_s_setprio(0);

    // row-max over own 32 scores + cross-half combine (verified shfl_xor)
    float mx = s0[0];
#pragma unroll
    for (int i = 1; i < 16; ++i) mx = fmaxf(mx, s0[i]);
#pragma unroll
    for (int i = 0; i < 16; ++i) mx = fmaxf(mx, s1[i]);
    mx = fmaxf(mx, __shfl_xor(mx, 32));
    // defer-max (T13, THR=8 in base-2 units => P <= 2^8)
    if (__any(mx > mval + 8.0f)) {
      const float mnew  = fmaxf(mval, mx);
      const float alpha = fexp2(mval - mnew);
      mval = mnew;
      lval *= alpha;
#pragma unroll
      for (int dh = 0; dh < 2; ++dh)
#pragma unroll
        for (int i = 0; i < 16; ++i) oAcc[dh][i] *= alpha;
    }
    // p = exp2(s - m), pack to bf16 words; w[m] = pack(regs 2m, 2m+1)
    float rs = 0.f;
    unsigned int w0[8], w1[8];
#pragma unroll
    for (int m = 0; m < 8; ++m) {
      const float p0 = fexp2(s0[2 * m] - mval);
      const float p1 = fexp2(s0[2 * m + 1] - mval);
      rs += p0 + p1;
      w0[m] = pack2(p0, p1);
    }
#pragma unroll
    for (int m = 0; m < 8; ++m) {
      const float p0 = fexp2(s1[2 * m] - mval);
      const float p1 = fexp2(s1[2 * m + 1] - mval);
      rs += p0 + p1;
      w1[m] = pack2(p0, p1);
    }
    rs += __shfl_xor(rs, 32);
    lval += rs;

    // P^T -> PV B-fragments via verified cross-half exchange
    union Cv { unsigned int w[4]; bf16x8_t v; };
    bf16x8_t pf[4];
    {
      const unsigned int e0 = exch32(w0[0]), e1 = exch32(w0[1]);
      const unsigned int e2 = exch32(w0[2]), e3 = exch32(w0[3]);
      Cv c;
      c.w[0] = hb ? e2 : w0[0]; c.w[1] = hb ? e3 : w0[1];
      c.w[2] = hb ? w0[2] : e0; c.w[3] = hb ? w0[3] : e1;
      pf[0] = c.v;
    }
    {
      const unsigned int e0 = exch32(w0[4]), e1 = exch32(w0[5]);
      const unsigned int e2 = exch32(w0[6]), e3 = exch32(w0[7]);
      Cv c;
      c.w[0] = hb ? e2 : w0[4]; c.w[1] = hb ? e3 : w0[5];
      c.w[2] = hb ? w0[6] : e0; c.w[3] = hb ? w0[7] : e1;
      pf[1] = c.v;
    }
    {
      const unsigned int e0 = exch32(w1[0]), e1 = exch32(w1[1]);
      const unsigned int e2 = exch32(w1[2]), e3 = exch32(w1[3]);
      Cv c;
      c.w[0] = hb ? e2 : w1[0]; c.w[1] = hb ? e3 : w1[1];
      c.w[2] = hb ? w1[2] : e0; c.w[3] = hb ? w1[3] : e1;
      pf[2] = c.v;
    }
    {
      const unsigned int e0 = exch32(w1[4]), e1 = exch32(w1[5]);
      const unsigned int e2 = exch32(w1[6]), e3 = exch32(w1[7]);
      Cv c;
      c.w[0] = hb ? e2 : w1[4]; c.w[1] = hb ? e3 : w1[5];
      c.w[2] = hb ? w1[6] : e0; c.w[3] = hb ? w1[7] : e1;
      pf[3] = c.v;
    }

    // O^T += V^T · P^T : A = V^T rows d = dh*32 + l31, keys 16t + hb*8 + j
    __builtin_amdgcn_s_setprio(1);
    {
      const unsigned short* vrow = vcur + l31 * 64;
#pragma unroll
      for (int t = 0; t < 4; ++t) {
        bf16x8_t vf = *(const bf16x8_t*)&vrow[((2 * t + hb) ^ swr0) << 3];
        oAcc[0] = __builtin_amdgcn_mfma_f32_32x32x16_bf16(vf, pf[t], oAcc[0], 0, 0, 0);
      }
    }
    {
      const unsigned short* vrow = vcur + (32 + l31) * 64;
#pragma unroll
      for (int t = 0; t < 4; ++t) {
        bf16x8_t vf = *(const bf16x8_t*)&vrow[((2 * t + hb) ^ swr1) << 3];
        oAcc[1] = __builtin_amdgcn_mfma_f32_32x32x16_bf16(vf, pf[t], oAcc[1], 0, 0, 0);
      }
    }
    __builtin_amdgcn_s_setprio(0);

    // single barrier per iter: drains this iter's prefetch (vmcnt) AND all waves' LDS reads
    __syncthreads();
    cur ^= 1;
  }
#undef STAGE

  // epilogue: lane owns q = q0+wv*32+l31; d = 32*dh + 8*a + 4*hb + c  (reg = 4a+c)
  const int bb = bh >> 4, hh = bh & 15;
  const float inv = 1.0f / lval;
  unsigned short* orow = Oattn + (size_t)(bb * SEQ + q0 + wv * 32 + l31) * D_MODEL
                       + hh * DK + hb * 4;
#pragma unroll
  for (int dh = 0; dh < 2; ++dh)
#pragma unroll
    for (int a = 0; a < 4; ++a) {
      const float v0 = oAcc[dh][4 * a]     * inv;
      const float v1 = oAcc[dh][4 * a + 1] * inv;
      const float v2 = oAcc[dh][4 * a + 2] * inv;
      const float v3 = oAcc[dh][4 * a + 3] * inv;
      *(uint2*)(orow + dh * 32 + a * 8) = make_uint2(pack2(v0, v1), pack2(v2, v3));
    }
}

extern "C" void kernel_launch(void* const* d_in, const int* in_sizes, int n_in,
                              void* d_out, int out_size, void* d_ws, size_t ws_size,
                              hipStream_t stream) {
  const float* query = (const float*)d_in[0];
  const float* key   = (const float*)d_in[1];
  const float* value = (const float*)d_in[2];
  const float* Wq    = (const float*)d_in[3];
  const float* bq    = (const float*)d_in[4];
  const float* Wk    = (const float*)d_in[5];
  const float* bk    = (const float*)d_in[6];
  const float* Wv    = (const float*)d_in[7];
  const float* bv    = (const float*)d_in[8];
  const float* Wo    = (const float*)d_in[9];
  const float* bo    = (const float*)d_in[10];

  const size_t E  = (size_t)BATCH * SEQ * D_MODEL;   // 8,388,608
  const size_t WE = (size_t)D_MODEL * D_MODEL;       // 1,048,576
  unsigned short* ws  = (unsigned short*)d_ws;
  unsigned short* Qws = ws;                          // [B,H,S,dk], pre-scaled log2e/8
  unsigned short* Kws = ws + E;
  unsigned short* Vws = ws + 2 * E;                  // [B,H,dk,S] transposed
  unsigned short* qb  = ws + 3 * E;
  unsigned short* kb  = ws + 4 * E;
  unsigned short* vb  = ws + 5 * E;
  unsigned short* wqb = ws + 6 * E;
  unsigned short* wkb = wqb + WE;
  unsigned short* wvb = wqb + 2 * WE;
  unsigned short* wob = wqb + 3 * WE;
  unsigned short* Aws = qb;                          // alias: qb dead after QKV GEMM

  cvt3_kernel<<<dim3(E / 2048, 3), 256, 0, stream>>>(query, key, value, qb, kb, vb);
  cvt4_kernel<<<dim3(WE / 2048, 4), 256, 0, stream>>>(Wq, Wk, Wv, Wo, wqb, wkb, wvb, wob);

  qkv_kernel<<<dim3(BATCH * SEQ / 128, D_MODEL / 128, 3), 256, 0, stream>>>(
      qb, kb, vb, wqb, wkb, wvb, bq, bk, bv, Qws, Kws, Vws);
  attn_kernel<<<dim3(BATCH * NHEADS, SEQ / 256), 512, 0, stream>>>(Qws, Kws, Vws, Aws);
  outproj_kernel<<<dim3(BATCH * SEQ / 128, D_MODEL / 128), 256, 0, stream>>>(
      Aws, wob, bo, (float*)d_out);
}

// Round 8
// 351.304 us; speedup vs baseline: 1.1457x; 1.0401x over previous
//
#include <hip/hip_runtime.h>
#include <hip/hip_bf16.h>
#include <cstdint>
#include <cstddef>

// MultiHeadAttention B=4, S=2048, D=1024, H=16, dk=64. fp32 in/out, bf16 MFMA internals.
// cvt fp32->bf16 (single fused launch) -> fused QKV gemm (Q/K via operand-SWAPPED mfma ->
// vectorized uint2 epilogue; V written transposed [B,H,dk,S]) -> flash attn (R7 structure,
// frozen: 8 waves x 32q swapped 32x32x16, zero bank conflicts) -> out proj (SWAPPED ->
// float4 epilogue).

#define BATCH   4
#define SEQ     2048
#define D_MODEL 1024
#define NHEADS  16
#define DK      64

typedef __attribute__((ext_vector_type(8)))  __bf16 bf16x8_t;
typedef __attribute__((ext_vector_type(4)))  float  f32x4;
typedef __attribute__((ext_vector_type(16))) float  f32x16;

// HW packed fp32->bf16 (v_cvt_pk_bf16_f32 on gfx950)
__device__ inline unsigned int pack2(float lo, float hi) {
  __hip_bfloat162 h = __float22bfloat162_rn(make_float2(lo, hi));
  union { __hip_bfloat162 h; unsigned int u; } c; c.h = h; return c.u;
}
__device__ inline unsigned short f2bf(float f) { return (unsigned short)pack2(f, f); }

#if __has_builtin(__builtin_amdgcn_exp2f)
__device__ inline float fexp2(float x) { return __builtin_amdgcn_exp2f(x); }
#else
__device__ inline float fexp2(float x) { return __expf(x * 0.6931471805599453f); }
#endif

__device__ inline unsigned int exch32(unsigned int x) {  // partner lane^32 (verified prim)
  return (unsigned int)__shfl_xor((int)x, 32);
}

__device__ inline void cvt8(const float* __restrict__ s, unsigned short* __restrict__ d) {
  const float4 a = *(const float4*)s;
  const float4 b = *(const float4*)(s + 4);
  uint4 r;
  r.x = pack2(a.x, a.y); r.y = pack2(a.z, a.w);
  r.z = pack2(b.x, b.y); r.w = pack2(b.z, b.w);
  *(uint4*)d = r;
}

// async global->LDS, 16B/lane; LDS dest = wave-uniform base + lane*16B
typedef __attribute__((address_space(3))) unsigned int lds_u32_t;
typedef const __attribute__((address_space(1))) unsigned int glb_u32_t;
__device__ inline void gld16(const unsigned short* g, unsigned short* l) {
  __builtin_amdgcn_global_load_lds((glb_u32_t*)(uintptr_t)g,
                                   (lds_u32_t*)(unsigned int)(uintptr_t)l, 16, 0, 0);
}

// ---------------- fused fp32 -> bf16 conversion (3 activations + 4 weights, one launch) ----------------
__global__ __launch_bounds__(256) void cvt7_kernel(
    const float* __restrict__ a, const float* __restrict__ b, const float* __restrict__ c,
    const float* __restrict__ w0, const float* __restrict__ w1,
    const float* __restrict__ w2, const float* __restrict__ w3,
    unsigned short* __restrict__ oa, unsigned short* __restrict__ ob, unsigned short* __restrict__ oc,
    unsigned short* __restrict__ ow0, unsigned short* __restrict__ ow1,
    unsigned short* __restrict__ ow2, unsigned short* __restrict__ ow3)
{
  const int bx = blockIdx.x;
  const float* s;
  unsigned short* d;
  size_t local;
  if (bx < 12288) {                      // 3 tensors x 4096 blocks (E elems each)
    const int t = bx >> 12;
    local = (size_t)(bx & 4095);
    s = (t == 0) ? a : (t == 1) ? b : c;
    d = (t == 0) ? oa : (t == 1) ? ob : oc;
  } else {                               // 4 weights x 512 blocks (WE elems each)
    const int t = (bx - 12288) >> 9;
    local = (size_t)((bx - 12288) & 511);
    s = (t == 0) ? w0 : (t == 1) ? w1 : (t == 2) ? w2 : w3;
    d = (t == 0) ? ow0 : (t == 1) ? ow1 : (t == 2) ? ow2 : ow3;
  }
  const size_t i = (local * 256 + threadIdx.x) * 8;
  cvt8(s + i, d + i);
}

// ---------------- shared GEMM core: acc += A[128 rows @m0] * W[128 rows @n0]^T ----------------
// m97 structure: BK=32 unpadded LDS, global_load_lds 16B, chunk^(row&3) source-side swizzle.
// SWAP=false: D[m=quad*4+reg, n=l15]  (C/D: col=lane&15, row=quad*4+reg [m89])
// SWAP=true : mfma(W,A) -> D[m=l15, n=quad*4+reg]  (operand-format symmetry proven by
//             attn's swapped QK^T in production R0-R7; XOR-swizzle k-chunks cancel: both
//             fragments deliver global k-chunk = quad*8.)
template <bool SWAP>
__device__ inline void gemm_core(const unsigned short* __restrict__ A,
                                 const unsigned short* __restrict__ W,
                                 unsigned short* a_lds, unsigned short* b_lds,
                                 int m0, int n0, f32x4 (&acc)[4][4])
{
  const int tid  = threadIdx.x;
  const int lane = tid & 63;
  const int wv   = tid >> 6;
  const int l15  = lane & 15;
  const int quad = lane >> 4;
  const int wm = (wv & 1) * 64;
  const int wn = (wv >> 1) * 64;

  const int srow = tid >> 2;
  const int sch  = (tid & 3) ^ (srow & 3);
  const unsigned short* Ap0 = A + (size_t)(m0 + srow) * D_MODEL + sch * 8;
  const unsigned short* Ap1 = Ap0 + (size_t)64 * D_MODEL;
  const unsigned short* Wp0 = W + (size_t)(n0 + srow) * D_MODEL + sch * 8;
  const unsigned short* Wp1 = Wp0 + (size_t)64 * D_MODEL;
  unsigned short* al0 = a_lds + wv * 512;
  unsigned short* al1 = a_lds + 2048 + wv * 512;
  unsigned short* bl0 = b_lds + wv * 512;
  unsigned short* bl1 = b_lds + 2048 + wv * 512;

  const int pq = (quad ^ (l15 & 3)) * 8;

  for (int k0 = 0; k0 < D_MODEL; k0 += 32) {
    __syncthreads();
    gld16(Ap0 + k0, al0);
    gld16(Ap1 + k0, al1);
    gld16(Wp0 + k0, bl0);
    gld16(Wp1 + k0, bl1);
    __syncthreads();

    bf16x8_t af[4], bfr[4];
#pragma unroll
    for (int i = 0; i < 4; ++i)
      af[i] = *(const bf16x8_t*)&a_lds[(wm + i * 16 + l15) * 32 + pq];
#pragma unroll
    for (int j = 0; j < 4; ++j)
      bfr[j] = *(const bf16x8_t*)&b_lds[(wn + j * 16 + l15) * 32 + pq];

#pragma unroll
    for (int i = 0; i < 4; ++i)
#pragma unroll
      for (int j = 0; j < 4; ++j) {
        if constexpr (SWAP)
          acc[i][j] = __builtin_amdgcn_mfma_f32_16x16x32_bf16(bfr[j], af[i], acc[i][j], 0, 0, 0);
        else
          acc[i][j] = __builtin_amdgcn_mfma_f32_16x16x32_bf16(af[i], bfr[j], acc[i][j], 0, 0, 0);
      }
  }
}

// ---------------- fused QKV projection ----------------
// grid (M/128, N/128, 3). z=0: Q (scaled log2e/8, SWAPPED -> uint2 scatter [B,H,S,dk]);
// z=1: K (SWAPPED -> uint2); z=2: V TRANSPOSED [B,H,dk,S] (non-swapped -> uint2).
__global__ __launch_bounds__(256) void qkv_kernel(
    const unsigned short* __restrict__ qb, const unsigned short* __restrict__ kb,
    const unsigned short* __restrict__ vb,
    const unsigned short* __restrict__ wq, const unsigned short* __restrict__ wk,
    const unsigned short* __restrict__ wvp,
    const float* __restrict__ bq, const float* __restrict__ bk, const float* __restrict__ bv,
    unsigned short* __restrict__ Qws, unsigned short* __restrict__ Kws,
    unsigned short* __restrict__ Vws)
{
  __shared__ unsigned short a_lds[128 * 32];
  __shared__ unsigned short b_lds[128 * 32];

  const int z = blockIdx.z;
  const unsigned short* A = (z == 0) ? qb : (z == 1) ? kb : vb;
  const unsigned short* W = (z == 0) ? wq : (z == 1) ? wk : wvp;
  const float* bias       = (z == 0) ? bq : (z == 1) ? bk : bv;
  unsigned short* C       = (z == 0) ? Qws : (z == 1) ? Kws : Vws;
  const int m0 = blockIdx.x * 128;
  const int n0 = blockIdx.y * 128;

  f32x4 acc[4][4];
#pragma unroll
  for (int i = 0; i < 4; ++i)
#pragma unroll
    for (int j = 0; j < 4; ++j)
      acc[i][j] = (f32x4){0.f, 0.f, 0.f, 0.f};

  const int tid  = threadIdx.x;
  const int lane = tid & 63;
  const int wv   = tid >> 6;
  const int l15  = lane & 15;
  const int quad = lane >> 4;
  const int wm = (wv & 1) * 64;
  const int wn = (wv >> 1) * 64;

  if (z == 2) {
    gemm_core<false>(A, W, a_lds, b_lds, m0, n0, acc);
    // D[m=quad*4+reg, n=l15]; V^T: off = ((bb*H+hh)*DK+dd)*SEQ + ss; 4 consecutive ss -> uint2
    for (int j = 0; j < 4; ++j) {
      const int n = n0 + wn + j * 16 + l15;
      const int hh = n >> 6, dd = n & 63;
      const float bvl = bias[n];
      for (int i = 0; i < 4; ++i) {
        const int mbase = m0 + wm + i * 16 + quad * 4;
        const int bb = mbase >> 11, ss = mbase & 2047;
        uint2 w2 = make_uint2(pack2(acc[i][j][0] + bvl, acc[i][j][1] + bvl),
                              pack2(acc[i][j][2] + bvl, acc[i][j][3] + bvl));
        *(uint2*)(C + (((size_t)bb * NHEADS + hh) * DK + dd) * SEQ + ss) = w2;
      }
    }
  } else {
    gemm_core<true>(A, W, a_lds, b_lds, m0, n0, acc);
    // SWAPPED: D[m=l15, n=quad*4+reg] -> 4 consecutive dd per lane (same head: quad*4+3<64)
    const float oscale = (z == 0) ? 0.18033688011112042f : 1.0f;  // log2(e)/8 for Q
    for (int j = 0; j < 4; ++j) {
      const int nb = n0 + wn + j * 16 + quad * 4;
      const int hh = nb >> 6, dd = nb & 63;
      const float4 b4 = *(const float4*)(bias + nb);
      for (int i = 0; i < 4; ++i) {
        const int m = m0 + wm + i * 16 + l15;
        const int bb = m >> 11, ss = m & 2047;
        uint2 w2 = make_uint2(pack2((acc[i][j][0] + b4.x) * oscale, (acc[i][j][1] + b4.y) * oscale),
                              pack2((acc[i][j][2] + b4.z) * oscale, (acc[i][j][3] + b4.w) * oscale));
        *(uint2*)(C + (((size_t)bb * NHEADS + hh) * SEQ + ss) * DK + dd) = w2;
      }
    }
  }
}

// ---------------- output projection (bf16 A, fp32 out, SWAPPED -> float4 epilogue) ----------------
__global__ __launch_bounds__(256) void outproj_kernel(
    const unsigned short* __restrict__ A, const unsigned short* __restrict__ W,
    const float* __restrict__ bias, float* __restrict__ C)
{
  __shared__ unsigned short a_lds[128 * 32];
  __shared__ unsigned short b_lds[128 * 32];
  const int m0 = blockIdx.x * 128;
  const int n0 = blockIdx.y * 128;

  f32x4 acc[4][4];
#pragma unroll
  for (int i = 0; i < 4; ++i)
#pragma unroll
    for (int j = 0; j < 4; ++j)
      acc[i][j] = (f32x4){0.f, 0.f, 0.f, 0.f};

  gemm_core<true>(A, W, a_lds, b_lds, m0, n0, acc);

  const int tid  = threadIdx.x;
  const int lane = tid & 63;
  const int wv   = tid >> 6;
  const int l15  = lane & 15;
  const int quad = lane >> 4;
  const int wm = (wv & 1) * 64;
  const int wn = (wv >> 1) * 64;
  // SWAPPED: D[m=l15, n=quad*4+reg] -> float4 store (nb 4-aligned -> 16B aligned)
  for (int j = 0; j < 4; ++j) {
    const int nb = n0 + wn + j * 16 + quad * 4;
    const float4 b4 = *(const float4*)(bias + nb);
    for (int i = 0; i < 4; ++i) {
      const int m = m0 + wm + i * 16 + l15;
      float4 o4 = make_float4(acc[i][j][0] + b4.x, acc[i][j][1] + b4.y,
                              acc[i][j][2] + b4.z, acc[i][j][3] + b4.w);
      *(float4*)(C + (size_t)m * D_MODEL + nb) = o4;
    }
  }
}

// ---------------- Flash attention, swapped 32x32x16 form (R7, frozen) ----------------
// 512 thr (8 waves), wave wv owns 32 q-rows (q0 + wv*32 + l31); grid (B*H, S/256).
// S^T[64k x 32q] = K·Q^T via 2 key-slices x 4 dk-slices of mfma_32x32x16.
//   C/D: col = lane&31 = q, row = (reg&3)+8*(reg>>2)+4*(lane>>5)  [m74/m101]
// Cross-half combines + P^T B-fragment build via __shfl_xor(.,32).
// K/V^T DMA-staged double-buffered, source-side XOR swizzle chunk^(row&7)^(row>>3).
__global__ __launch_bounds__(512, 4) void attn_kernel(
    const unsigned short* __restrict__ Q,    // [B,H,S,dk]
    const unsigned short* __restrict__ K,    // [B,H,S,dk]
    const unsigned short* __restrict__ Vt,   // [B,H,dk,S]  (pre-transposed)
    unsigned short* __restrict__ Oattn)      // [B,S,D]
{
  __shared__ unsigned short k_sw[2 * 64 * 64];
  __shared__ unsigned short vt_sw[2 * 64 * 64];

  const int tid  = threadIdx.x;
  const int lane = tid & 63;
  const int wv   = tid >> 6;              // 0..7
  const int l31  = lane & 31;
  const int hb   = lane >> 5;             // half index
  const int bh   = blockIdx.x;            // bh-major: XCD = bh%8 -> K/V L2 locality
  const int q0   = blockIdx.y * 256;
  const size_t hoff = (size_t)bh * SEQ * DK;
  const unsigned short* Qh  = Q  + hoff;
  const unsigned short* Kh  = K  + hoff;
  const unsigned short* Vth = Vt + hoff;

  // Q fragments: q = q0 + wv*32 + l31, dk = kk*16 + hb*8 + j
  bf16x8_t qf[4];
  {
    const unsigned short* qr = Qh + (size_t)(q0 + wv * 32 + l31) * DK;
#pragma unroll
    for (int kk = 0; kk < 4; ++kk)
      qf[kk] = *(const bf16x8_t*)(qr + kk * 16 + hb * 8);
  }

  f32x16 oAcc[2];
#pragma unroll
  for (int dh = 0; dh < 2; ++dh)
#pragma unroll
    for (int i = 0; i < 16; ++i) oAcc[dh][i] = 0.f;
  float mval = -1e30f, lval = 0.f;

  // DMA staging: wave wv covers tile rows [wv*8, wv*8+8) of K and of V^T (1 gld16 each).
  const int sr  = lane >> 3;              // 0..7 (row within the wave's 8-row slab)
  const int pc  = lane & 7;               // phys chunk
  const int row = wv * 8 + sr;
  const int sem = pc ^ sr ^ wv;           // (row&7)=sr, (row>>3)=wv
  const unsigned short* KsA = Kh  + (size_t)row * DK  + sem * 8;   // + key0*DK per iter
  const unsigned short* VsA = Vth + (size_t)row * SEQ + sem * 8;   // + key0 per iter
  unsigned short* kd = k_sw  + wv * 512;
  unsigned short* vd = vt_sw + wv * 512;

#define STAGE(buf, key0) do {                                        \
    gld16(KsA + (size_t)(key0) * DK, kd + (buf) * 4096);             \
    gld16(VsA + (key0),              vd + (buf) * 4096);             \
  } while (0)

  // prologue: stage tile 0 into buffer 0
  STAGE(0, 0);
  __syncthreads();                         // drains vmcnt(0): tile 0 resident

  const int swr0 = (l31 & 7) ^ (l31 >> 3);         // swizzle for rows l31      (slice 0)
  const int swr1 = (l31 & 7) ^ ((l31 >> 3) ^ 4);   // swizzle for rows 32+l31   (slice 1)

  int cur = 0;
  for (int kb = 0; kb < SEQ / 64; ++kb) {
    // issue next tile's loads FIRST so they overlap this tile's compute
    if (kb + 1 < SEQ / 64) STAGE(cur ^ 1, (kb + 1) * 64);

    const unsigned short* kcur = k_sw  + cur * 4096;
    const unsigned short* vcur = vt_sw + cur * 4096;

    // S^T = K·Q^T : s0 = keys 0..31 rows, s1 = keys 32..63 rows (per C/D row map)
    f32x16 s0, s1;
#pragma unroll
    for (int i = 0; i < 16; ++i) { s0[i] = 0.f; s1[i] = 0.f; }
    __builtin_amdgcn_s_setprio(1);
    {
      const unsigned short* krow = kcur + l31 * 64;
#pragma unroll
      for (int kk = 0; kk < 4; ++kk) {
        bf16x8_t kf = *(const bf16x8_t*)&krow[((2 * kk + hb) ^ swr0) << 3];
        s0 = __builtin_amdgcn_mfma_f32_32x32x16_bf16(kf, qf[kk], s0, 0, 0, 0);
      }
    }
    {
      const unsigned short* krow = kcur + (32 + l31) * 64;
#pragma unroll
      for (int kk = 0; kk < 4; ++kk) {
        bf16x8_t kf = *(const bf16x8_t*)&krow[((2 * kk + hb) ^ swr1) << 3];
        s1 = __builtin_amdgcn_mfma_f32_32x32x16_bf16(kf, qf[kk], s1, 0, 0, 0);
      }
    }
    __builtin_amdgcn_s_setprio(0);

    // row-max over own 32 scores + cross-half combine (verified shfl_xor)
    float mx = s0[0];
#pragma unroll
    for (int i = 1; i < 16; ++i) mx = fmaxf(mx, s0[i]);
#pragma unroll
    for (int i = 0; i < 16; ++i) mx = fmaxf(mx, s1[i]);
    mx = fmaxf(mx, __shfl_xor(mx, 32));
    // defer-max (T13, THR=8 in base-2 units => P <= 2^8)
    if (__any(mx > mval + 8.0f)) {
      const float mnew  = fmaxf(mval, mx);
      const float alpha = fexp2(mval - mnew);
      mval = mnew;
      lval *= alpha;
#pragma unroll
      for (int dh = 0; dh < 2; ++dh)
#pragma unroll
        for (int i = 0; i < 16; ++i) oAcc[dh][i] *= alpha;
    }
    // p = exp2(s - m), pack to bf16 words; w[m] = pack(regs 2m, 2m+1)
    float rs = 0.f;
    unsigned int w0[8], w1[8];
#pragma unroll
    for (int m = 0; m < 8; ++m) {
      const float p0 = fexp2(s0[2 * m] - mval);
      const float p1 = fexp2(s0[2 * m + 1] - mval);
      rs += p0 + p1;
      w0[m] = pack2(p0, p1);
    }
#pragma unroll
    for (int m = 0; m < 8; ++m) {
      const float p0 = fexp2(s1[2 * m] - mval);
      const float p1 = fexp2(s1[2 * m + 1] - mval);
      rs += p0 + p1;
      w1[m] = pack2(p0, p1);
    }
    rs += __shfl_xor(rs, 32);
    lval += rs;

    // P^T -> PV B-fragments via verified cross-half exchange
    union Cv { unsigned int w[4]; bf16x8_t v; };
    bf16x8_t pf[4];
    {
      const unsigned int e0 = exch32(w0[0]), e1 = exch32(w0[1]);
      const unsigned int e2 = exch32(w0[2]), e3 = exch32(w0[3]);
      Cv c;
      c.w[0] = hb ? e2 : w0[0]; c.w[1] = hb ? e3 : w0[1];
      c.w[2] = hb ? w0[2] : e0; c.w[3] = hb ? w0[3] : e1;
      pf[0] = c.v;
    }
    {
      const unsigned int e0 = exch32(w0[4]), e1 = exch32(w0[5]);
      const unsigned int e2 = exch32(w0[6]), e3 = exch32(w0[7]);
      Cv c;
      c.w[0] = hb ? e2 : w0[4]; c.w[1] = hb ? e3 : w0[5];
      c.w[2] = hb ? w0[6] : e0; c.w[3] = hb ? w0[7] : e1;
      pf[1] = c.v;
    }
    {
      const unsigned int e0 = exch32(w1[0]), e1 = exch32(w1[1]);
      const unsigned int e2 = exch32(w1[2]), e3 = exch32(w1[3]);
      Cv c;
      c.w[0] = hb ? e2 : w1[0]; c.w[1] = hb ? e3 : w1[1];
      c.w[2] = hb ? w1[2] : e0; c.w[3] = hb ? w1[3] : e1;
      pf[2] = c.v;
    }
    {
      const unsigned int e0 = exch32(w1[4]), e1 = exch32(w1[5]);
      const unsigned int e2 = exch32(w1[6]), e3 = exch32(w1[7]);
      Cv c;
      c.w[0] = hb ? e2 : w1[4]; c.w[1] = hb ? e3 : w1[5];
      c.w[2] = hb ? w1[6] : e0; c.w[3] = hb ? w1[7] : e1;
      pf[3] = c.v;
    }

    // O^T += V^T · P^T : A = V^T rows d = dh*32 + l31, keys 16t + hb*8 + j
    __builtin_amdgcn_s_setprio(1);
    {
      const unsigned short* vrow = vcur + l31 * 64;
#pragma unroll
      for (int t = 0; t < 4; ++t) {
        bf16x8_t vf = *(const bf16x8_t*)&vrow[((2 * t + hb) ^ swr0) << 3];
        oAcc[0] = __builtin_amdgcn_mfma_f32_32x32x16_bf16(vf, pf[t], oAcc[0], 0, 0, 0);
      }
    }
    {
      const unsigned short* vrow = vcur + (32 + l31) * 64;
#pragma unroll
      for (int t = 0; t < 4; ++t) {
        bf16x8_t vf = *(const bf16x8_t*)&vrow[((2 * t + hb) ^ swr1) << 3];
        oAcc[1] = __builtin_amdgcn_mfma_f32_32x32x16_bf16(vf, pf[t], oAcc[1], 0, 0, 0);
      }
    }
    __builtin_amdgcn_s_setprio(0);

    // single barrier per iter: drains this iter's prefetch (vmcnt) AND all waves' LDS reads
    __syncthreads();
    cur ^= 1;
  }
#undef STAGE

  // epilogue: lane owns q = q0+wv*32+l31; d = 32*dh + 8*a + 4*hb + c  (reg = 4a+c)
  const int bb = bh >> 4, hh = bh & 15;
  const float inv = 1.0f / lval;
  unsigned short* orow = Oattn + (size_t)(bb * SEQ + q0 + wv * 32 + l31) * D_MODEL
                       + hh * DK + hb * 4;
#pragma unroll
  for (int dh = 0; dh < 2; ++dh)
#pragma unroll
    for (int a = 0; a < 4; ++a) {
      const float v0 = oAcc[dh][4 * a]     * inv;
      const float v1 = oAcc[dh][4 * a + 1] * inv;
      const float v2 = oAcc[dh][4 * a + 2] * inv;
      const float v3 = oAcc[dh][4 * a + 3] * inv;
      *(uint2*)(orow + dh * 32 + a * 8) = make_uint2(pack2(v0, v1), pack2(v2, v3));
    }
}

extern "C" void kernel_launch(void* const* d_in, const int* in_sizes, int n_in,
                              void* d_out, int out_size, void* d_ws, size_t ws_size,
                              hipStream_t stream) {
  const float* query = (const float*)d_in[0];
  const float* key   = (const float*)d_in[1];
  const float* value = (const float*)d_in[2];
  const float* Wq    = (const float*)d_in[3];
  const float* bq    = (const float*)d_in[4];
  const float* Wk    = (const float*)d_in[5];
  const float* bk    = (const float*)d_in[6];
  const float* Wv    = (const float*)d_in[7];
  const float* bv    = (const float*)d_in[8];
  const float* Wo    = (const float*)d_in[9];
  const float* bo    = (const float*)d_in[10];

  const size_t E  = (size_t)BATCH * SEQ * D_MODEL;   // 8,388,608
  const size_t WE = (size_t)D_MODEL * D_MODEL;       // 1,048,576
  unsigned short* ws  = (unsigned short*)d_ws;
  unsigned short* Qws = ws;                          // [B,H,S,dk], pre-scaled log2e/8
  unsigned short* Kws = ws + E;
  unsigned short* Vws = ws + 2 * E;                  // [B,H,dk,S] transposed
  unsigned short* qb  = ws + 3 * E;
  unsigned short* kb  = ws + 4 * E;
  unsigned short* vb  = ws + 5 * E;
  unsigned short* wqb = ws + 6 * E;
  unsigned short* wkb = wqb + WE;
  unsigned short* wvb = wqb + 2 * WE;
  unsigned short* wob = wqb + 3 * WE;
  unsigned short* Aws = qb;                          // alias: qb dead after QKV GEMM

  cvt7_kernel<<<dim3(12288 + 2048), 256, 0, stream>>>(
      query, key, value, Wq, Wk, Wv, Wo, qb, kb, vb, wqb, wkb, wvb, wob);

  qkv_kernel<<<dim3(BATCH * SEQ / 128, D_MODEL / 128, 3), 256, 0, stream>>>(
      qb, kb, vb, wqb, wkb, wvb, bq, bk, bv, Qws, Kws, Vws);
  attn_kernel<<<dim3(BATCH * NHEADS, SEQ / 256), 512, 0, stream>>>(Qws, Kws, Vws, Aws);
  outproj_kernel<<<dim3(BATCH * SEQ / 128, D_MODEL / 128), 256, 0, stream>>>(
      Aws, wob, bo, (float*)d_out);
}